// Round 2
// baseline (1849.720 us; speedup 1.0000x reference)
//
#include <hip/hip_runtime.h>
#include <stdint.h>

// Problem constants: D=64 in-features, 2D=128 hidden.
#define D  64
#define D2 128

// ---------------------------------------------------------------------------
// Kernel 1: edge message + scatter-add (all fp32).
// 16 threads per edge; thread p handles features [4p, 4p+4) via float4.
// msg (fp32) must be pre-zeroed.
// ---------------------------------------------------------------------------
__global__ __launch_bounds__(256) void k_edge(
    const float* __restrict__ nf,
    const int* __restrict__ ef,       // [E,3]
    const int* __restrict__ ei,       // [2,E]: row0 = dst, row1 = src
    const float* __restrict__ be0,    // [5,64]
    const float* __restrict__ be1,    // [6,64]
    const float* __restrict__ be2,    // [2,64]
    float* __restrict__ msg, int E)
{
    int t = blockIdx.x * 256 + threadIdx.x;
    int e = t >> 4;
    int p = t & 15;
    if (e >= E) return;
    int dst = ei[e];
    int src = ei[E + e];
    int f0 = ef[3 * e + 0];
    int f1 = ef[3 * e + 1];
    int f2 = ef[3 * e + 2];
    float4 a  = ((const float4*)(nf  + (size_t)src * D))[p];
    float4 e0 = ((const float4*)(be0 + (size_t)f0  * D))[p];
    float4 e1 = ((const float4*)(be1 + (size_t)f1  * D))[p];
    float4 e2 = ((const float4*)(be2 + (size_t)f2  * D))[p];
    float m0 = fmaxf(a.x + e0.x + e1.x + e2.x, 0.0f);
    float m1 = fmaxf(a.y + e0.y + e1.y + e2.y, 0.0f);
    float m2 = fmaxf(a.z + e0.z + e1.z + e2.z, 0.0f);
    float m3 = fmaxf(a.w + e0.w + e1.w + e2.w, 0.0f);
    float* q = msg + (size_t)dst * D + p * 4;
    atomicAdd(q + 0, m0);
    atomicAdd(q + 1, m1);
    atomicAdd(q + 2, m2);
    atomicAdd(q + 3, m3);
}

// ---------------------------------------------------------------------------
// Kernel 2: h1 = ((1+eps)*x + msg) @ W1^T + b1  -> column sum / sumsq only.
// 256 threads, 32 rows per block. Thread (ty=tid/32, tx=tid%32) computes a
// 4x4 register tile: rows ty*4..+3, cols tx*4..+3 (128 cols total).
// ---------------------------------------------------------------------------
__global__ __launch_bounds__(256) void k_gemm1_stats(
    const float* __restrict__ nf,
    const float* __restrict__ msg,
    const float* __restrict__ W1,    // [128,64]
    const float* __restrict__ b1,    // [128]
    const float* __restrict__ epsp,  // [1]
    float* __restrict__ stats,       // [256]: sum[128], sumsq[128]
    int N)
{
    __shared__ float A[32 * 68];     // h tile [32][68 pad]
    __shared__ float Wt[64 * 132];   // W1 transposed: [k][c], row pad 132

    int tid  = threadIdx.x;
    int row0 = blockIdx.x * 32;
    float epsv = 1.0f + epsp[0];

    // ---- stage 0: load h tile ----
    {
        int r  = tid >> 3;
        int c8 = tid & 7;           // which group of 8 cols
        int gr = row0 + r;
        float* dstp = &A[r * 68 + c8 * 8];
        if (gr < N) {
            const float4* nrow = (const float4*)(nf  + (size_t)gr * D);
            const float4* mrow = (const float4*)(msg + (size_t)gr * D);
            float4 n0 = nrow[c8 * 2],     n1 = nrow[c8 * 2 + 1];
            float4 m0 = mrow[c8 * 2],     m1 = mrow[c8 * 2 + 1];
            dstp[0] = fmaf(epsv, n0.x, m0.x);
            dstp[1] = fmaf(epsv, n0.y, m0.y);
            dstp[2] = fmaf(epsv, n0.z, m0.z);
            dstp[3] = fmaf(epsv, n0.w, m0.w);
            dstp[4] = fmaf(epsv, n1.x, m1.x);
            dstp[5] = fmaf(epsv, n1.y, m1.y);
            dstp[6] = fmaf(epsv, n1.z, m1.z);
            dstp[7] = fmaf(epsv, n1.w, m1.w);
        } else {
            #pragma unroll
            for (int n = 0; n < 8; n++) dstp[n] = 0.0f;
        }
    }
    // ---- load W1 transposed into LDS: Wt[k][c] ----
    {
        int c  = tid >> 1;          // output channel 0..127
        int k0 = (tid & 1) * 32;
        const float4* wr = (const float4*)(W1 + c * D + k0);
        #pragma unroll
        for (int q = 0; q < 8; q++) {
            float4 u = wr[q];
            int k = k0 + q * 4;
            Wt[(k + 0) * 132 + c] = u.x;
            Wt[(k + 1) * 132 + c] = u.y;
            Wt[(k + 2) * 132 + c] = u.z;
            Wt[(k + 3) * 132 + c] = u.w;
        }
    }
    __syncthreads();

    int ty = tid >> 5, tx = tid & 31;
    float acc[4][4];
    #pragma unroll
    for (int i = 0; i < 4; i++)
        #pragma unroll
        for (int j = 0; j < 4; j++) acc[i][j] = 0.0f;

    #pragma unroll 8
    for (int k = 0; k < D; k++) {
        float4 b = *(const float4*)&Wt[k * 132 + tx * 4];
        #pragma unroll
        for (int i = 0; i < 4; i++) {
            float a = A[(ty * 4 + i) * 68 + k];
            acc[i][0] = fmaf(a, b.x, acc[i][0]);
            acc[i][1] = fmaf(a, b.y, acc[i][1]);
            acc[i][2] = fmaf(a, b.z, acc[i][2]);
            acc[i][3] = fmaf(a, b.w, acc[i][3]);
        }
    }

    float bb0 = b1[tx * 4 + 0];
    float bb1 = b1[tx * 4 + 1];
    float bb2 = b1[tx * 4 + 2];
    float bb3 = b1[tx * 4 + 3];

    float s[4] = {0, 0, 0, 0}, q[4] = {0, 0, 0, 0};
    #pragma unroll
    for (int i = 0; i < 4; i++) {
        if (row0 + ty * 4 + i < N) {
            float h0 = acc[i][0] + bb0;
            float h1 = acc[i][1] + bb1;
            float h2 = acc[i][2] + bb2;
            float h3 = acc[i][3] + bb3;
            s[0] += h0; q[0] += h0 * h0;
            s[1] += h1; q[1] += h1 * h1;
            s[2] += h2; q[2] += h2 * h2;
            s[3] += h3; q[3] += h3 * h3;
        }
    }
    __syncthreads();   // done reading A; reuse as reduction scratch
    {
        float* red = A;
        #pragma unroll
        for (int n = 0; n < 4; n++) { red[tid * 8 + n] = s[n]; red[tid * 8 + 4 + n] = q[n]; }
        __syncthreads();
        if (tid < 32) {
            float r8[8] = {0, 0, 0, 0, 0, 0, 0, 0};
            for (int g = 0; g < 8; g++) {
                const float* srcp = &red[(g * 32 + tid) * 8];
                #pragma unroll
                for (int n = 0; n < 8; n++) r8[n] += srcp[n];
            }
            #pragma unroll
            for (int j = 0; j < 4; j++) {
                atomicAdd(&stats[tid * 4 + j],        r8[j]);
                atomicAdd(&stats[128 + tid * 4 + j],  r8[4 + j]);
            }
        }
    }
}

// ---------------------------------------------------------------------------
// Kernel 3: finalize BN -> per-column scale/shift (fp32).
// ---------------------------------------------------------------------------
__global__ void k_finalize(
    const float* __restrict__ stats,
    const float* __restrict__ gamma,
    const float* __restrict__ beta,
    float* __restrict__ ss,   // [256]: scale[128], shift[128]
    float invN)
{
    int c = threadIdx.x;  // 128 threads
    float mean = stats[c] * invN;
    float var  = fmaxf(stats[128 + c] * invN - mean * mean, 0.0f);
    float sc   = gamma[c] * rsqrtf(var + 1e-5f);
    ss[c]       = sc;
    ss[128 + c] = beta[c] - mean * sc;
}

// ---------------------------------------------------------------------------
// Kernel 4: recompute h1, apply BN+ReLU, GEMM with W2^T, write fp32 out.
// ---------------------------------------------------------------------------
__global__ __launch_bounds__(256) void k_gemm2(
    const float* __restrict__ nf,
    const float* __restrict__ msg,
    const float* __restrict__ W1,    // [128,64]
    const float* __restrict__ b1,    // [128]
    const float* __restrict__ epsp,
    const float* __restrict__ ss,    // scale/shift
    const float* __restrict__ W2,    // [64,128]
    const float* __restrict__ b2v,   // [64]
    float* __restrict__ out,         // [N,64]
    int N)
{
    __shared__ float A[32 * 68];     // h tile
    __shared__ float Wt[64 * 132];   // stage1: W1t [64][132]; stage2: W2t [128][66]
    __shared__ float B[32 * 132];    // g = relu(bn(h1)) tile [32][132]

    int tid  = threadIdx.x;
    int row0 = blockIdx.x * 32;
    float epsv = 1.0f + epsp[0];

    // ---- stage 0: load h tile ----
    {
        int r  = tid >> 3;
        int c8 = tid & 7;
        int gr = row0 + r;
        float* dstp = &A[r * 68 + c8 * 8];
        if (gr < N) {
            const float4* nrow = (const float4*)(nf  + (size_t)gr * D);
            const float4* mrow = (const float4*)(msg + (size_t)gr * D);
            float4 n0 = nrow[c8 * 2],     n1 = nrow[c8 * 2 + 1];
            float4 m0 = mrow[c8 * 2],     m1 = mrow[c8 * 2 + 1];
            dstp[0] = fmaf(epsv, n0.x, m0.x);
            dstp[1] = fmaf(epsv, n0.y, m0.y);
            dstp[2] = fmaf(epsv, n0.z, m0.z);
            dstp[3] = fmaf(epsv, n0.w, m0.w);
            dstp[4] = fmaf(epsv, n1.x, m1.x);
            dstp[5] = fmaf(epsv, n1.y, m1.y);
            dstp[6] = fmaf(epsv, n1.z, m1.z);
            dstp[7] = fmaf(epsv, n1.w, m1.w);
        } else {
            #pragma unroll
            for (int n = 0; n < 8; n++) dstp[n] = 0.0f;
        }
    }
    {
        int c  = tid >> 1;
        int k0 = (tid & 1) * 32;
        const float4* wr = (const float4*)(W1 + c * D + k0);
        #pragma unroll
        for (int q = 0; q < 8; q++) {
            float4 u = wr[q];
            int k = k0 + q * 4;
            Wt[(k + 0) * 132 + c] = u.x;
            Wt[(k + 1) * 132 + c] = u.y;
            Wt[(k + 2) * 132 + c] = u.z;
            Wt[(k + 3) * 132 + c] = u.w;
        }
    }
    __syncthreads();

    int ty = tid >> 5, tx = tid & 31;
    float acc[4][4];
    #pragma unroll
    for (int i = 0; i < 4; i++)
        #pragma unroll
        for (int j = 0; j < 4; j++) acc[i][j] = 0.0f;

    #pragma unroll 8
    for (int k = 0; k < D; k++) {
        float4 b = *(const float4*)&Wt[k * 132 + tx * 4];
        #pragma unroll
        for (int i = 0; i < 4; i++) {
            float a = A[(ty * 4 + i) * 68 + k];
            acc[i][0] = fmaf(a, b.x, acc[i][0]);
            acc[i][1] = fmaf(a, b.y, acc[i][1]);
            acc[i][2] = fmaf(a, b.z, acc[i][2]);
            acc[i][3] = fmaf(a, b.w, acc[i][3]);
        }
    }

    {
        float bb0 = b1[tx * 4 + 0];
        float bb1 = b1[tx * 4 + 1];
        float bb2 = b1[tx * 4 + 2];
        float bb3 = b1[tx * 4 + 3];
        float4 scv = *(const float4*)&ss[tx * 4];
        float4 shv = *(const float4*)&ss[128 + tx * 4];
        #pragma unroll
        for (int i = 0; i < 4; i++) {
            float g0 = fmaxf(fmaf(acc[i][0] + bb0, scv.x, shv.x), 0.0f);
            float g1 = fmaxf(fmaf(acc[i][1] + bb1, scv.y, shv.y), 0.0f);
            float g2 = fmaxf(fmaf(acc[i][2] + bb2, scv.z, shv.z), 0.0f);
            float g3 = fmaxf(fmaf(acc[i][3] + bb3, scv.w, shv.w), 0.0f);
            float4* bp = (float4*)&B[(ty * 4 + i) * 132 + tx * 4];
            *bp = make_float4(g0, g1, g2, g3);
        }
    }
    __syncthreads();   // all reads of W1t done; all B writes visible

    // ---- load W2 transposed: W2t[k][j], row pad 66 ----
    {
        int j  = tid >> 2;          // 0..63
        int k0 = (tid & 3) * 32;
        const float4* wr = (const float4*)(W2 + j * D2 + k0);
        #pragma unroll
        for (int q = 0; q < 8; q++) {
            float4 u = wr[q];
            int k = k0 + q * 4;
            Wt[(k + 0) * 66 + j] = u.x;
            Wt[(k + 1) * 66 + j] = u.y;
            Wt[(k + 2) * 66 + j] = u.z;
            Wt[(k + 3) * 66 + j] = u.w;
        }
    }
    __syncthreads();

    float acc2[4][2];
    #pragma unroll
    for (int i = 0; i < 4; i++) { acc2[i][0] = 0.0f; acc2[i][1] = 0.0f; }

    #pragma unroll 8
    for (int k = 0; k < D2; k++) {
        float2 b = *(const float2*)&Wt[k * 66 + tx * 2];
        #pragma unroll
        for (int i = 0; i < 4; i++) {
            float a = B[(ty * 4 + i) * 132 + k];
            acc2[i][0] = fmaf(a, b.x, acc2[i][0]);
            acc2[i][1] = fmaf(a, b.y, acc2[i][1]);
        }
    }

    float ob0 = b2v[tx * 2 + 0];
    float ob1 = b2v[tx * 2 + 1];
    #pragma unroll
    for (int i = 0; i < 4; i++) {
        int gr = row0 + ty * 4 + i;
        if (gr < N) {
            float2 pk = make_float2(acc2[i][0] + ob0, acc2[i][1] + ob1);
            ((float2*)out)[(size_t)gr * 32 + tx] = pk;
        }
    }
}

// ---------------------------------------------------------------------------
extern "C" void kernel_launch(void* const* d_in, const int* in_sizes, int n_in,
                              void* d_out, int out_size, void* d_ws, size_t ws_size,
                              hipStream_t stream)
{
    const float* nf    = (const float*)d_in[0];
    const int*   ef    = (const int*)d_in[1];
    const int*   ei    = (const int*)d_in[2];
    // d_in[3] = num_nodes, d_in[4] = num_edges (device scalars; sizes suffice)
    const float* epsp  = (const float*)d_in[5];
    const float* be0   = (const float*)d_in[6];
    const float* be1   = (const float*)d_in[7];
    const float* be2   = (const float*)d_in[8];
    const float* W1    = (const float*)d_in[9];
    const float* b1    = (const float*)d_in[10];
    const float* gamma = (const float*)d_in[11];
    const float* beta  = (const float*)d_in[12];
    const float* W2    = (const float*)d_in[13];
    const float* b2v   = (const float*)d_in[14];
    float*       out   = (float*)d_out;

    int N = in_sizes[0] / D;    // 100000
    int E = in_sizes[1] / 3;    // 1600000

    float* msg   = (float*)d_ws;                 // N*64 fp32 accumulator
    float* stats = msg + (size_t)N * D;          // 256 fp32 (sum, sumsq)
    float* ss    = stats + 256;                  // 256 fp32 (scale, shift)

    // zero msg + stats (ws is re-poisoned before every timed launch)
    hipMemsetAsync(d_ws, 0, ((size_t)N * D + 256) * sizeof(float), stream);

    int edgeBlocks = (E * 16 + 255) / 256;       // 16 threads per edge
    k_edge<<<edgeBlocks, 256, 0, stream>>>(nf, ef, ei, be0, be1, be2, msg, E);

    int rowBlocks = (N + 31) / 32;
    k_gemm1_stats<<<rowBlocks, 256, 0, stream>>>(nf, msg, W1, b1, epsp, stats, N);

    k_finalize<<<1, 128, 0, stream>>>(stats, gamma, beta, ss, 1.0f / (float)N);

    k_gemm2<<<rowBlocks, 256, 0, stream>>>(nf, msg, W1, b1, epsp, ss, W2, b2v, out, N);
}

// Round 3
// 817.207 us; speedup vs baseline: 2.2635x; 2.2635x over previous
//
#include <hip/hip_runtime.h>
#include <stdint.h>

// Problem constants: D=64 in-features, 2D=128 hidden.
#define D  64
#define D2 128
#define CHUNK 1024   // elements per scan1 block

// ---------------------------------------------------------------------------
// Embedding-sum table: embsum[code][0:64], code = f0*12 + f1*2 + f2 (60 codes)
// ---------------------------------------------------------------------------
__global__ void k_embsum(
    const float* __restrict__ be0,   // [5,64]
    const float* __restrict__ be1,   // [6,64]
    const float* __restrict__ be2,   // [2,64]
    float* __restrict__ embsum)      // [60,64]
{
    int c = blockIdx.x;      // 0..59
    int t = threadIdx.x;     // 0..63
    int f0 = c / 12;
    int r  = c % 12;
    int f1 = r / 2;
    int f2 = r % 2;
    embsum[c * D + t] = be0[f0 * D + t] + be1[f1 * D + t] + be2[f2 * D + t];
}

// ---------------------------------------------------------------------------
// Histogram of dst. cnt must be pre-zeroed.
// ---------------------------------------------------------------------------
__global__ __launch_bounds__(256) void k_hist(
    const int* __restrict__ ei, int* __restrict__ cnt, int E)
{
    int e = blockIdx.x * 256 + threadIdx.x;
    if (e >= E) return;
    atomicAdd(&cnt[ei[e]], 1);
}

// ---------------------------------------------------------------------------
// Scan step 1: per-block (1024 elems) exclusive scan into offs, block sums out.
// ---------------------------------------------------------------------------
__global__ __launch_bounds__(256) void k_scan1(
    const int* __restrict__ cnt, int* __restrict__ offs,
    int* __restrict__ bsum, int N)
{
    __shared__ int sd[256];
    int t    = threadIdx.x;
    int base = blockIdx.x * CHUNK;
    int i0   = base + t * 4;
    int v0 = (i0 + 0 < N) ? cnt[i0 + 0] : 0;
    int v1 = (i0 + 1 < N) ? cnt[i0 + 1] : 0;
    int v2 = (i0 + 2 < N) ? cnt[i0 + 2] : 0;
    int v3 = (i0 + 3 < N) ? cnt[i0 + 3] : 0;
    int s = v0 + v1 + v2 + v3;
    sd[t] = s;
    __syncthreads();
    for (int off = 1; off < 256; off <<= 1) {
        int x = (t >= off) ? sd[t - off] : 0;
        __syncthreads();
        sd[t] += x;
        __syncthreads();
    }
    int excl = sd[t] - s;
    if (t == 255) bsum[blockIdx.x] = sd[255];
    if (i0 + 0 < N) offs[i0 + 0] = excl;
    if (i0 + 1 < N) offs[i0 + 1] = excl + v0;
    if (i0 + 2 < N) offs[i0 + 2] = excl + v0 + v1;
    if (i0 + 3 < N) offs[i0 + 3] = excl + v0 + v1 + v2;
}

// ---------------------------------------------------------------------------
// Scan step 2: scan the (<=128) block sums. Single block of 128 threads.
// ---------------------------------------------------------------------------
__global__ void k_scan2(const int* __restrict__ bsum, int* __restrict__ boff, int NB)
{
    __shared__ int sd[128];
    int t = threadIdx.x;
    int v = (t < NB) ? bsum[t] : 0;
    sd[t] = v;
    __syncthreads();
    for (int off = 1; off < 128; off <<= 1) {
        int x = (t >= off) ? sd[t - off] : 0;
        __syncthreads();
        sd[t] += x;
        __syncthreads();
    }
    if (t < NB) boff[t] = sd[t] - v;   // exclusive
}

// ---------------------------------------------------------------------------
// Scan step 3: add block offsets; produce offs (final) and cursor copy in cnt.
// ---------------------------------------------------------------------------
__global__ __launch_bounds__(256) void k_scan3(
    int* __restrict__ offs, int* __restrict__ cnt,
    const int* __restrict__ boff, int N, int E)
{
    int i = blockIdx.x * 256 + threadIdx.x;
    if (i < N) {
        int o = offs[i] + boff[i / CHUNK];
        offs[i] = o;
        cnt[i]  = o;    // cursor for scatter
    }
    if (i == 0) offs[N] = E;
}

// ---------------------------------------------------------------------------
// Scatter: payload[pos] = src | (code<<17), pos from per-dst cursor.
// ---------------------------------------------------------------------------
__global__ __launch_bounds__(256) void k_scatter(
    const int* __restrict__ ei, const int* __restrict__ ef,
    int* __restrict__ cursor, int* __restrict__ payload, int E)
{
    int e = blockIdx.x * 256 + threadIdx.x;
    if (e >= E) return;
    int dst = ei[e];
    int src = ei[E + e];
    int f0 = ef[3 * e + 0];
    int f1 = ef[3 * e + 1];
    int f2 = ef[3 * e + 2];
    int code = f0 * 12 + f1 * 2 + f2;
    int pos = atomicAdd(&cursor[dst], 1);
    payload[pos] = src | (code << 17);
}

// ---------------------------------------------------------------------------
// Gather-reduce: one wave per node, lane = feature. No atomics.
// ---------------------------------------------------------------------------
__global__ __launch_bounds__(256) void k_reduce(
    const float* __restrict__ nf,
    const int* __restrict__ offs,
    const int* __restrict__ payload,
    const float* __restrict__ embsum,
    float* __restrict__ msg, int N)
{
    __shared__ float sE[60 * D];   // 15 KB
    int tid = threadIdx.x;
    for (int i = tid; i < 60 * D; i += 256) sE[i] = embsum[i];
    __syncthreads();

    int n = (blockIdx.x * 256 + tid) >> 6;   // node for this wave
    int l = tid & 63;                        // feature lane
    if (n >= N) return;

    int start = offs[n];
    int end   = offs[n + 1];
    float acc = 0.0f;
    for (int jb = start; jb < end; jb += 64) {
        int u = (jb + l < end) ? payload[jb + l] : 0;   // coalesced batch
        int m = end - jb; if (m > 64) m = 64;
        for (int t = 0; t < m; t++) {
            int ut   = __shfl(u, t);
            int src  = ut & 0x1FFFF;
            int code = ut >> 17;
            float x = nf[(size_t)src * D + l] + sE[code * D + l];
            acc += fmaxf(x, 0.0f);
        }
    }
    msg[(size_t)n * D + l] = acc;
}

// ---------------------------------------------------------------------------
// GEMM1 + BN stats (unchanged from passing round-2 version).
// ---------------------------------------------------------------------------
__global__ __launch_bounds__(256) void k_gemm1_stats(
    const float* __restrict__ nf,
    const float* __restrict__ msg,
    const float* __restrict__ W1,    // [128,64]
    const float* __restrict__ b1,    // [128]
    const float* __restrict__ epsp,  // [1]
    float* __restrict__ stats,       // [256]: sum[128], sumsq[128]
    int N)
{
    __shared__ float A[32 * 68];
    __shared__ float Wt[64 * 132];

    int tid  = threadIdx.x;
    int row0 = blockIdx.x * 32;
    float epsv = 1.0f + epsp[0];

    {
        int r  = tid >> 3;
        int c8 = tid & 7;
        int gr = row0 + r;
        float* dstp = &A[r * 68 + c8 * 8];
        if (gr < N) {
            const float4* nrow = (const float4*)(nf  + (size_t)gr * D);
            const float4* mrow = (const float4*)(msg + (size_t)gr * D);
            float4 n0 = nrow[c8 * 2],     n1 = nrow[c8 * 2 + 1];
            float4 m0 = mrow[c8 * 2],     m1 = mrow[c8 * 2 + 1];
            dstp[0] = fmaf(epsv, n0.x, m0.x);
            dstp[1] = fmaf(epsv, n0.y, m0.y);
            dstp[2] = fmaf(epsv, n0.z, m0.z);
            dstp[3] = fmaf(epsv, n0.w, m0.w);
            dstp[4] = fmaf(epsv, n1.x, m1.x);
            dstp[5] = fmaf(epsv, n1.y, m1.y);
            dstp[6] = fmaf(epsv, n1.z, m1.z);
            dstp[7] = fmaf(epsv, n1.w, m1.w);
        } else {
            #pragma unroll
            for (int n = 0; n < 8; n++) dstp[n] = 0.0f;
        }
    }
    {
        int c  = tid >> 1;
        int k0 = (tid & 1) * 32;
        const float4* wr = (const float4*)(W1 + c * D + k0);
        #pragma unroll
        for (int q = 0; q < 8; q++) {
            float4 u = wr[q];
            int k = k0 + q * 4;
            Wt[(k + 0) * 132 + c] = u.x;
            Wt[(k + 1) * 132 + c] = u.y;
            Wt[(k + 2) * 132 + c] = u.z;
            Wt[(k + 3) * 132 + c] = u.w;
        }
    }
    __syncthreads();

    int ty = tid >> 5, tx = tid & 31;
    float acc[4][4];
    #pragma unroll
    for (int i = 0; i < 4; i++)
        #pragma unroll
        for (int j = 0; j < 4; j++) acc[i][j] = 0.0f;

    #pragma unroll 8
    for (int k = 0; k < D; k++) {
        float4 b = *(const float4*)&Wt[k * 132 + tx * 4];
        #pragma unroll
        for (int i = 0; i < 4; i++) {
            float a = A[(ty * 4 + i) * 68 + k];
            acc[i][0] = fmaf(a, b.x, acc[i][0]);
            acc[i][1] = fmaf(a, b.y, acc[i][1]);
            acc[i][2] = fmaf(a, b.z, acc[i][2]);
            acc[i][3] = fmaf(a, b.w, acc[i][3]);
        }
    }

    float bb0 = b1[tx * 4 + 0];
    float bb1 = b1[tx * 4 + 1];
    float bb2 = b1[tx * 4 + 2];
    float bb3 = b1[tx * 4 + 3];

    float s[4] = {0, 0, 0, 0}, q[4] = {0, 0, 0, 0};
    #pragma unroll
    for (int i = 0; i < 4; i++) {
        if (row0 + ty * 4 + i < N) {
            float h0 = acc[i][0] + bb0;
            float h1 = acc[i][1] + bb1;
            float h2 = acc[i][2] + bb2;
            float h3 = acc[i][3] + bb3;
            s[0] += h0; q[0] += h0 * h0;
            s[1] += h1; q[1] += h1 * h1;
            s[2] += h2; q[2] += h2 * h2;
            s[3] += h3; q[3] += h3 * h3;
        }
    }
    __syncthreads();
    {
        float* red = A;
        #pragma unroll
        for (int n = 0; n < 4; n++) { red[tid * 8 + n] = s[n]; red[tid * 8 + 4 + n] = q[n]; }
        __syncthreads();
        if (tid < 32) {
            float r8[8] = {0, 0, 0, 0, 0, 0, 0, 0};
            for (int g = 0; g < 8; g++) {
                const float* srcp = &red[(g * 32 + tid) * 8];
                #pragma unroll
                for (int n = 0; n < 8; n++) r8[n] += srcp[n];
            }
            #pragma unroll
            for (int j = 0; j < 4; j++) {
                atomicAdd(&stats[tid * 4 + j],        r8[j]);
                atomicAdd(&stats[128 + tid * 4 + j],  r8[4 + j]);
            }
        }
    }
}

// ---------------------------------------------------------------------------
__global__ void k_finalize(
    const float* __restrict__ stats,
    const float* __restrict__ gamma,
    const float* __restrict__ beta,
    float* __restrict__ ss,
    float invN)
{
    int c = threadIdx.x;  // 128 threads
    float mean = stats[c] * invN;
    float var  = fmaxf(stats[128 + c] * invN - mean * mean, 0.0f);
    float sc   = gamma[c] * rsqrtf(var + 1e-5f);
    ss[c]       = sc;
    ss[128 + c] = beta[c] - mean * sc;
}

// ---------------------------------------------------------------------------
// GEMM2 (unchanged from passing round-2 version).
// ---------------------------------------------------------------------------
__global__ __launch_bounds__(256) void k_gemm2(
    const float* __restrict__ nf,
    const float* __restrict__ msg,
    const float* __restrict__ W1,
    const float* __restrict__ b1,
    const float* __restrict__ epsp,
    const float* __restrict__ ss,
    const float* __restrict__ W2,
    const float* __restrict__ b2v,
    float* __restrict__ out,
    int N)
{
    __shared__ float A[32 * 68];
    __shared__ float Wt[64 * 132];
    __shared__ float B[32 * 132];

    int tid  = threadIdx.x;
    int row0 = blockIdx.x * 32;
    float epsv = 1.0f + epsp[0];

    {
        int r  = tid >> 3;
        int c8 = tid & 7;
        int gr = row0 + r;
        float* dstp = &A[r * 68 + c8 * 8];
        if (gr < N) {
            const float4* nrow = (const float4*)(nf  + (size_t)gr * D);
            const float4* mrow = (const float4*)(msg + (size_t)gr * D);
            float4 n0 = nrow[c8 * 2],     n1 = nrow[c8 * 2 + 1];
            float4 m0 = mrow[c8 * 2],     m1 = mrow[c8 * 2 + 1];
            dstp[0] = fmaf(epsv, n0.x, m0.x);
            dstp[1] = fmaf(epsv, n0.y, m0.y);
            dstp[2] = fmaf(epsv, n0.z, m0.z);
            dstp[3] = fmaf(epsv, n0.w, m0.w);
            dstp[4] = fmaf(epsv, n1.x, m1.x);
            dstp[5] = fmaf(epsv, n1.y, m1.y);
            dstp[6] = fmaf(epsv, n1.z, m1.z);
            dstp[7] = fmaf(epsv, n1.w, m1.w);
        } else {
            #pragma unroll
            for (int n = 0; n < 8; n++) dstp[n] = 0.0f;
        }
    }
    {
        int c  = tid >> 1;
        int k0 = (tid & 1) * 32;
        const float4* wr = (const float4*)(W1 + c * D + k0);
        #pragma unroll
        for (int q = 0; q < 8; q++) {
            float4 u = wr[q];
            int k = k0 + q * 4;
            Wt[(k + 0) * 132 + c] = u.x;
            Wt[(k + 1) * 132 + c] = u.y;
            Wt[(k + 2) * 132 + c] = u.z;
            Wt[(k + 3) * 132 + c] = u.w;
        }
    }
    __syncthreads();

    int ty = tid >> 5, tx = tid & 31;
    float acc[4][4];
    #pragma unroll
    for (int i = 0; i < 4; i++)
        #pragma unroll
        for (int j = 0; j < 4; j++) acc[i][j] = 0.0f;

    #pragma unroll 8
    for (int k = 0; k < D; k++) {
        float4 b = *(const float4*)&Wt[k * 132 + tx * 4];
        #pragma unroll
        for (int i = 0; i < 4; i++) {
            float a = A[(ty * 4 + i) * 68 + k];
            acc[i][0] = fmaf(a, b.x, acc[i][0]);
            acc[i][1] = fmaf(a, b.y, acc[i][1]);
            acc[i][2] = fmaf(a, b.z, acc[i][2]);
            acc[i][3] = fmaf(a, b.w, acc[i][3]);
        }
    }

    {
        float bb0 = b1[tx * 4 + 0];
        float bb1 = b1[tx * 4 + 1];
        float bb2 = b1[tx * 4 + 2];
        float bb3 = b1[tx * 4 + 3];
        float4 scv = *(const float4*)&ss[tx * 4];
        float4 shv = *(const float4*)&ss[128 + tx * 4];
        #pragma unroll
        for (int i = 0; i < 4; i++) {
            float g0 = fmaxf(fmaf(acc[i][0] + bb0, scv.x, shv.x), 0.0f);
            float g1 = fmaxf(fmaf(acc[i][1] + bb1, scv.y, shv.y), 0.0f);
            float g2 = fmaxf(fmaf(acc[i][2] + bb2, scv.z, shv.z), 0.0f);
            float g3 = fmaxf(fmaf(acc[i][3] + bb3, scv.w, shv.w), 0.0f);
            float4* bp = (float4*)&B[(ty * 4 + i) * 132 + tx * 4];
            *bp = make_float4(g0, g1, g2, g3);
        }
    }
    __syncthreads();

    {
        int j  = tid >> 2;
        int k0 = (tid & 3) * 32;
        const float4* wr = (const float4*)(W2 + j * D2 + k0);
        #pragma unroll
        for (int q = 0; q < 8; q++) {
            float4 u = wr[q];
            int k = k0 + q * 4;
            Wt[(k + 0) * 66 + j] = u.x;
            Wt[(k + 1) * 66 + j] = u.y;
            Wt[(k + 2) * 66 + j] = u.z;
            Wt[(k + 3) * 66 + j] = u.w;
        }
    }
    __syncthreads();

    float acc2[4][2];
    #pragma unroll
    for (int i = 0; i < 4; i++) { acc2[i][0] = 0.0f; acc2[i][1] = 0.0f; }

    #pragma unroll 8
    for (int k = 0; k < D2; k++) {
        float2 b = *(const float2*)&Wt[k * 66 + tx * 2];
        #pragma unroll
        for (int i = 0; i < 4; i++) {
            float a = B[(ty * 4 + i) * 132 + k];
            acc2[i][0] = fmaf(a, b.x, acc2[i][0]);
            acc2[i][1] = fmaf(a, b.y, acc2[i][1]);
        }
    }

    float ob0 = b2v[tx * 2 + 0];
    float ob1 = b2v[tx * 2 + 1];
    #pragma unroll
    for (int i = 0; i < 4; i++) {
        int gr = row0 + ty * 4 + i;
        if (gr < N) {
            float2 pk = make_float2(acc2[i][0] + ob0, acc2[i][1] + ob1);
            ((float2*)out)[(size_t)gr * 32 + tx] = pk;
        }
    }
}

// ---------------------------------------------------------------------------
extern "C" void kernel_launch(void* const* d_in, const int* in_sizes, int n_in,
                              void* d_out, int out_size, void* d_ws, size_t ws_size,
                              hipStream_t stream)
{
    const float* nf    = (const float*)d_in[0];
    const int*   ef    = (const int*)d_in[1];
    const int*   ei    = (const int*)d_in[2];
    const float* epsp  = (const float*)d_in[5];
    const float* be0   = (const float*)d_in[6];
    const float* be1   = (const float*)d_in[7];
    const float* be2   = (const float*)d_in[8];
    const float* W1    = (const float*)d_in[9];
    const float* b1    = (const float*)d_in[10];
    const float* gamma = (const float*)d_in[11];
    const float* beta  = (const float*)d_in[12];
    const float* W2    = (const float*)d_in[13];
    const float* b2v   = (const float*)d_in[14];
    float*       out   = (float*)d_out;

    int N = in_sizes[0] / D;    // 100000
    int E = in_sizes[1] / 3;    // 1600000
    int NB = (N + CHUNK - 1) / CHUNK;   // 98

    // workspace layout (all 4-byte elements)
    float* msg    = (float*)d_ws;                  // N*64
    float* stats  = msg + (size_t)N * D;           // 256
    float* ss     = stats + 256;                   // 256
    float* embsum = ss + 256;                      // 60*64
    int*   cnt    = (int*)(embsum + 60 * D);       // N (cursor after scan3)
    int*   offs   = cnt + N;                       // N+1
    int*   bsum   = offs + N + 1;                  // NB
    int*   boff   = bsum + NB;                     // NB
    int*   payload= boff + NB;                     // E

    // zero stats (256 floats) and cnt (N ints)
    hipMemsetAsync(stats, 0, 256 * sizeof(float), stream);
    hipMemsetAsync(cnt,   0, (size_t)N * sizeof(int), stream);

    k_embsum<<<60, 64, 0, stream>>>(be0, be1, be2, embsum);

    int eBlocks = (E + 255) / 256;
    k_hist<<<eBlocks, 256, 0, stream>>>(ei, cnt, E);
    k_scan1<<<NB, 256, 0, stream>>>(cnt, offs, bsum, N);
    k_scan2<<<1, 128, 0, stream>>>(bsum, boff, NB);
    k_scan3<<<(N + 255) / 256, 256, 0, stream>>>(offs, cnt, boff, N, E);
    k_scatter<<<eBlocks, 256, 0, stream>>>(ei, ef, cnt, payload, E);

    k_reduce<<<(N + 3) / 4, 256, 0, stream>>>(nf, offs, payload, embsum, msg, N);

    int rowBlocks = (N + 31) / 32;
    k_gemm1_stats<<<rowBlocks, 256, 0, stream>>>(nf, msg, W1, b1, epsp, stats, N);
    k_finalize<<<1, 128, 0, stream>>>(stats, gamma, beta, ss, 1.0f / (float)N);
    k_gemm2<<<rowBlocks, 256, 0, stream>>>(nf, msg, W1, b1, epsp, ss, W2, b2v, out, N);
}

// Round 5
// 677.411 us; speedup vs baseline: 2.7306x; 1.2064x over previous
//
#include <hip/hip_runtime.h>
#include <stdint.h>

#define D  64
#define D2 128
#define CHUNK 1024

// ---------------------------------------------------------------------------
// Embedding-sum table: embsum[code][0:64], code = f0*12 + f1*2 + f2 (60 codes)
// ---------------------------------------------------------------------------
__global__ void k_embsum(
    const float* __restrict__ be0, const float* __restrict__ be1,
    const float* __restrict__ be2, float* __restrict__ embsum)
{
    int c = blockIdx.x;      // 0..59
    int t = threadIdx.x;     // 0..63
    int f0 = c / 12;
    int r  = c % 12;
    int f1 = r / 2;
    int f2 = r % 2;
    embsum[c * D + t] = be0[f0 * D + t] + be1[f1 * D + t] + be2[f2 * D + t];
}

// ---------------------------------------------------------------------------
__global__ __launch_bounds__(256) void k_hist(
    const int* __restrict__ ei, int* __restrict__ cnt, int E)
{
    int e = blockIdx.x * 256 + threadIdx.x;
    if (e >= E) return;
    atomicAdd(&cnt[ei[e]], 1);
}

// ---------------------------------------------------------------------------
__global__ __launch_bounds__(256) void k_scan1(
    const int* __restrict__ cnt, int* __restrict__ offs,
    int* __restrict__ bsum, int N)
{
    __shared__ int sd[256];
    int t    = threadIdx.x;
    int i0   = blockIdx.x * CHUNK + t * 4;
    int v0 = (i0 + 0 < N) ? cnt[i0 + 0] : 0;
    int v1 = (i0 + 1 < N) ? cnt[i0 + 1] : 0;
    int v2 = (i0 + 2 < N) ? cnt[i0 + 2] : 0;
    int v3 = (i0 + 3 < N) ? cnt[i0 + 3] : 0;
    int s = v0 + v1 + v2 + v3;
    sd[t] = s;
    __syncthreads();
    for (int off = 1; off < 256; off <<= 1) {
        int x = (t >= off) ? sd[t - off] : 0;
        __syncthreads();
        sd[t] += x;
        __syncthreads();
    }
    int excl = sd[t] - s;
    if (t == 255) bsum[blockIdx.x] = sd[255];
    if (i0 + 0 < N) offs[i0 + 0] = excl;
    if (i0 + 1 < N) offs[i0 + 1] = excl + v0;
    if (i0 + 2 < N) offs[i0 + 2] = excl + v0 + v1;
    if (i0 + 3 < N) offs[i0 + 3] = excl + v0 + v1 + v2;
}

__global__ void k_scan2(const int* __restrict__ bsum, int* __restrict__ boff, int NB)
{
    __shared__ int sd[128];
    int t = threadIdx.x;
    int v = (t < NB) ? bsum[t] : 0;
    sd[t] = v;
    __syncthreads();
    for (int off = 1; off < 128; off <<= 1) {
        int x = (t >= off) ? sd[t - off] : 0;
        __syncthreads();
        sd[t] += x;
        __syncthreads();
    }
    if (t < NB) boff[t] = sd[t] - v;
}

__global__ __launch_bounds__(256) void k_scan3(
    int* __restrict__ offs, int* __restrict__ cnt,
    const int* __restrict__ boff, int N, int E)
{
    int i = blockIdx.x * 256 + threadIdx.x;
    if (i < N) {
        int o = offs[i] + boff[i / CHUNK];
        offs[i] = o;
        cnt[i]  = o;
    }
    if (i == 0) offs[N] = E;
}

// ---------------------------------------------------------------------------
__global__ __launch_bounds__(256) void k_scatter(
    const int* __restrict__ ei, const int* __restrict__ ef,
    int* __restrict__ cursor, int* __restrict__ payload, int E)
{
    int e = blockIdx.x * 256 + threadIdx.x;
    if (e >= E) return;
    int dst = ei[e];
    int src = ei[E + e];
    int code = ef[3 * e + 0] * 12 + ef[3 * e + 1] * 2 + ef[3 * e + 2];
    int pos = atomicAdd(&cursor[dst], 1);
    payload[pos] = src | (code << 17);
}

// ---------------------------------------------------------------------------
// Gather-reduce + fuse h = (1+eps)*nf + msg. One wave per node, lane=feature.
// ---------------------------------------------------------------------------
__global__ __launch_bounds__(256) void k_reduce(
    const float* __restrict__ nf,
    const int* __restrict__ offs,
    const int* __restrict__ payload,
    const float* __restrict__ embsum,
    const float* __restrict__ epsp,
    float* __restrict__ h, int N)
{
    __shared__ float sE[60 * D];   // 15 KB
    int tid = threadIdx.x;
    for (int i = tid; i < 60 * D; i += 256) sE[i] = embsum[i];
    __syncthreads();

    int n = (blockIdx.x * 256 + tid) >> 6;
    int l = tid & 63;
    if (n >= N) return;

    int start = offs[n];
    int end   = offs[n + 1];
    float acc = 0.0f;
    for (int jb = start; jb < end; jb += 64) {
        int u = (jb + l < end) ? payload[jb + l] : 0;
        int m = end - jb; if (m > 64) m = 64;
        for (int t = 0; t < m; t++) {
            int ut   = __shfl(u, t);
            int src  = ut & 0x1FFFF;
            int code = ut >> 17;
            float x = nf[(size_t)src * D + l] + sE[code * D + l];
            acc += fmaxf(x, 0.0f);
        }
    }
    float epsv = 1.0f + epsp[0];
    h[(size_t)n * D + l] = fmaf(epsv, nf[(size_t)n * D + l], acc);
}

// ---------------------------------------------------------------------------
// GEMM1 + BN stats. Persistent blocks, 64-row tiles, W1 staged once.
// Stats -> register accumulation -> per-block partials (NO global atomics).
// Thread (ty=tid/32, tx=tid%32): rows ty*8..+7, cols tx*4..+3.
// ---------------------------------------------------------------------------
__global__ __launch_bounds__(256) void k_gemm1_stats(
    const float* __restrict__ h,
    const float* __restrict__ W1,    // [128,64]
    const float* __restrict__ b1,    // [128]
    float* __restrict__ partials,    // [grid][256]: sum[128], sumsq[128]
    int N, int tiles)
{
    __shared__ float A[64 * 68];     // 17408 B (reused as reduction scratch)
    __shared__ float Wt[64 * 132];   // W1^T [k][c], 33792 B

    int tid = threadIdx.x;
    int ty = tid >> 5, tx = tid & 31;

    // stage W1^T once
    {
        int c  = tid >> 1;
        int k0 = (tid & 1) * 32;
        const float4* wr = (const float4*)(W1 + c * D + k0);
        #pragma unroll
        for (int q = 0; q < 8; q++) {
            float4 u = wr[q];
            int k = k0 + q * 4;
            Wt[(k + 0) * 132 + c] = u.x;
            Wt[(k + 1) * 132 + c] = u.y;
            Wt[(k + 2) * 132 + c] = u.z;
            Wt[(k + 3) * 132 + c] = u.w;
        }
    }

    float bb0 = b1[tx * 4 + 0];
    float bb1 = b1[tx * 4 + 1];
    float bb2 = b1[tx * 4 + 2];
    float bb3 = b1[tx * 4 + 3];

    float s[4] = {0, 0, 0, 0}, q[4] = {0, 0, 0, 0};

    for (int t = blockIdx.x; t < tiles; t += gridDim.x) {
        int row0 = t * 64;
        __syncthreads();   // protect A from previous iteration's reads (& Wt staging, iter 0)
        {
            int r  = tid >> 2;
            int c16 = (tid & 3) * 16;
            int gr = row0 + r;
            float* dstp = &A[r * 68 + c16];
            if (gr < N) {
                const float4* hrow = (const float4*)(h + (size_t)gr * D + c16);
                #pragma unroll
                for (int m = 0; m < 4; m++) ((float4*)dstp)[m] = hrow[m];
            } else {
                #pragma unroll
                for (int m = 0; m < 16; m++) dstp[m] = 0.0f;
            }
        }
        __syncthreads();

        float acc[8][4];
        #pragma unroll
        for (int i = 0; i < 8; i++)
            #pragma unroll
            for (int j = 0; j < 4; j++) acc[i][j] = 0.0f;

        #pragma unroll 4
        for (int k4 = 0; k4 < 16; k4++) {
            float4 w0 = *(const float4*)&Wt[(k4 * 4 + 0) * 132 + tx * 4];
            float4 w1 = *(const float4*)&Wt[(k4 * 4 + 1) * 132 + tx * 4];
            float4 w2 = *(const float4*)&Wt[(k4 * 4 + 2) * 132 + tx * 4];
            float4 w3 = *(const float4*)&Wt[(k4 * 4 + 3) * 132 + tx * 4];
            #pragma unroll
            for (int i = 0; i < 8; i++) {
                float4 a = *(const float4*)&A[(ty * 8 + i) * 68 + k4 * 4];
                acc[i][0] = fmaf(a.x, w0.x, acc[i][0]);
                acc[i][1] = fmaf(a.x, w0.y, acc[i][1]);
                acc[i][2] = fmaf(a.x, w0.z, acc[i][2]);
                acc[i][3] = fmaf(a.x, w0.w, acc[i][3]);
                acc[i][0] = fmaf(a.y, w1.x, acc[i][0]);
                acc[i][1] = fmaf(a.y, w1.y, acc[i][1]);
                acc[i][2] = fmaf(a.y, w1.z, acc[i][2]);
                acc[i][3] = fmaf(a.y, w1.w, acc[i][3]);
                acc[i][0] = fmaf(a.z, w2.x, acc[i][0]);
                acc[i][1] = fmaf(a.z, w2.y, acc[i][1]);
                acc[i][2] = fmaf(a.z, w2.z, acc[i][2]);
                acc[i][3] = fmaf(a.z, w2.w, acc[i][3]);
                acc[i][0] = fmaf(a.w, w3.x, acc[i][0]);
                acc[i][1] = fmaf(a.w, w3.y, acc[i][1]);
                acc[i][2] = fmaf(a.w, w3.z, acc[i][2]);
                acc[i][3] = fmaf(a.w, w3.w, acc[i][3]);
            }
        }

        #pragma unroll
        for (int i = 0; i < 8; i++) {
            if (row0 + ty * 8 + i < N) {
                float h0 = acc[i][0] + bb0;
                float h1 = acc[i][1] + bb1;
                float h2 = acc[i][2] + bb2;
                float h3 = acc[i][3] + bb3;
                s[0] += h0; q[0] += h0 * h0;
                s[1] += h1; q[1] += h1 * h1;
                s[2] += h2; q[2] += h2 * h2;
                s[3] += h3; q[3] += h3 * h3;
            }
        }
    }

    // block-level reduce of stats into partials[blockIdx.x][256]
    __syncthreads();
    float* red = A;
    #pragma unroll
    for (int n = 0; n < 4; n++) { red[tid * 8 + n] = s[n]; red[tid * 8 + 4 + n] = q[n]; }
    __syncthreads();
    if (tid < 32) {
        float r8[8] = {0, 0, 0, 0, 0, 0, 0, 0};
        for (int g = 0; g < 8; g++) {
            const float* srcp = &red[(g * 32 + tid) * 8];
            #pragma unroll
            for (int n = 0; n < 8; n++) r8[n] += srcp[n];
        }
        float* P = partials + (size_t)blockIdx.x * 256;
        #pragma unroll
        for (int j = 0; j < 4; j++) {
            P[tid * 4 + j]       = r8[j];
            P[128 + tid * 4 + j] = r8[4 + j];
        }
    }
}

// ---------------------------------------------------------------------------
__global__ void k_stats_final(
    const float* __restrict__ partials, int nblk,
    const float* __restrict__ gamma, const float* __restrict__ beta,
    float* __restrict__ ss, float invN)
{
    int c = threadIdx.x;  // 128 threads
    float s = 0.0f, q = 0.0f;
    for (int b = 0; b < nblk; b++) {
        s += partials[(size_t)b * 256 + c];
        q += partials[(size_t)b * 256 + 128 + c];
    }
    float mean = s * invN;
    float var  = fmaxf(q * invN - mean * mean, 0.0f);
    float sc   = gamma[c] * rsqrtf(var + 1e-5f);
    ss[c]       = sc;
    ss[128 + c] = beta[c] - mean * sc;
}

// ---------------------------------------------------------------------------
// GEMM2: persistent blocks, 32-row tiles, W1t/W2t staged once.
// AB overlay buffer with UNIFORM pitch 132 for both phases:
//   phase A: h tile, cols 0..63;  phase B: relu(bn(h1)), cols 0..127.
// (Round-4 bug: B phase used pitch 68 -> row aliasing. Fixed.)
// Thread (ty,tx): rows ty*4..+3; stage1 cols tx*4..+3; stage2 cols tx*2..+1.
// ---------------------------------------------------------------------------
__global__ __launch_bounds__(256) void k_gemm2(
    const float* __restrict__ h,
    const float* __restrict__ W1,    // [128,64]
    const float* __restrict__ b1,    // [128]
    const float* __restrict__ ss,    // scale/shift [256]
    const float* __restrict__ W2,    // [64,128]
    const float* __restrict__ b2v,   // [64]
    float* __restrict__ out,         // [N,64]
    int N, int tiles)
{
    __shared__ float AB[32 * 132];    // 16896 B, pitch 132 both phases
    __shared__ float W1t[64 * 132];   // 33792 B
    __shared__ float W2t[128 * 66];   // 33792 B

    int tid = threadIdx.x;
    int ty = tid >> 5, tx = tid & 31;

    {   // stage W1^T
        int c  = tid >> 1;
        int k0 = (tid & 1) * 32;
        const float4* wr = (const float4*)(W1 + c * D + k0);
        #pragma unroll
        for (int q = 0; q < 8; q++) {
            float4 u = wr[q];
            int k = k0 + q * 4;
            W1t[(k + 0) * 132 + c] = u.x;
            W1t[(k + 1) * 132 + c] = u.y;
            W1t[(k + 2) * 132 + c] = u.z;
            W1t[(k + 3) * 132 + c] = u.w;
        }
    }
    {   // stage W2^T
        int j  = tid >> 2;
        int k0 = (tid & 3) * 32;
        const float4* wr = (const float4*)(W2 + j * D2 + k0);
        #pragma unroll
        for (int q = 0; q < 8; q++) {
            float4 u = wr[q];
            int k = k0 + q * 4;
            W2t[(k + 0) * 66 + j] = u.x;
            W2t[(k + 1) * 66 + j] = u.y;
            W2t[(k + 2) * 66 + j] = u.z;
            W2t[(k + 3) * 66 + j] = u.w;
        }
    }

    float bb0 = b1[tx * 4 + 0];
    float bb1 = b1[tx * 4 + 1];
    float bb2 = b1[tx * 4 + 2];
    float bb3 = b1[tx * 4 + 3];
    float4 scv = *(const float4*)&ss[tx * 4];
    float4 shv = *(const float4*)&ss[128 + tx * 4];
    float ob0 = b2v[tx * 2 + 0];
    float ob1 = b2v[tx * 2 + 1];

    for (int t = blockIdx.x; t < tiles; t += gridDim.x) {
        int row0 = t * 32;
        __syncthreads();   // protect AB from previous stage-2 reads (& W staging, iter 0)
        {   // phase A: stage h tile (cols 0..63)
            int r  = tid >> 3;
            int c8 = (tid & 7) * 8;
            int gr = row0 + r;
            float* dstp = &AB[r * 132 + c8];
            if (gr < N) {
                const float4* hrow = (const float4*)(h + (size_t)gr * D + c8);
                ((float4*)dstp)[0] = hrow[0];
                ((float4*)dstp)[1] = hrow[1];
            } else {
                #pragma unroll
                for (int m = 0; m < 8; m++) dstp[m] = 0.0f;
            }
        }
        __syncthreads();

        float acc[4][4];
        #pragma unroll
        for (int i = 0; i < 4; i++)
            #pragma unroll
            for (int j = 0; j < 4; j++) acc[i][j] = 0.0f;

        #pragma unroll 4
        for (int k4 = 0; k4 < 16; k4++) {
            float4 w0 = *(const float4*)&W1t[(k4 * 4 + 0) * 132 + tx * 4];
            float4 w1 = *(const float4*)&W1t[(k4 * 4 + 1) * 132 + tx * 4];
            float4 w2 = *(const float4*)&W1t[(k4 * 4 + 2) * 132 + tx * 4];
            float4 w3 = *(const float4*)&W1t[(k4 * 4 + 3) * 132 + tx * 4];
            #pragma unroll
            for (int i = 0; i < 4; i++) {
                float4 a = *(const float4*)&AB[(ty * 4 + i) * 132 + k4 * 4];
                acc[i][0] = fmaf(a.x, w0.x, acc[i][0]);
                acc[i][1] = fmaf(a.x, w0.y, acc[i][1]);
                acc[i][2] = fmaf(a.x, w0.z, acc[i][2]);
                acc[i][3] = fmaf(a.x, w0.w, acc[i][3]);
                acc[i][0] = fmaf(a.y, w1.x, acc[i][0]);
                acc[i][1] = fmaf(a.y, w1.y, acc[i][1]);
                acc[i][2] = fmaf(a.y, w1.z, acc[i][2]);
                acc[i][3] = fmaf(a.y, w1.w, acc[i][3]);
                acc[i][0] = fmaf(a.z, w2.x, acc[i][0]);
                acc[i][1] = fmaf(a.z, w2.y, acc[i][1]);
                acc[i][2] = fmaf(a.z, w2.z, acc[i][2]);
                acc[i][3] = fmaf(a.z, w2.w, acc[i][3]);
                acc[i][0] = fmaf(a.w, w3.x, acc[i][0]);
                acc[i][1] = fmaf(a.w, w3.y, acc[i][1]);
                acc[i][2] = fmaf(a.w, w3.z, acc[i][2]);
                acc[i][3] = fmaf(a.w, w3.w, acc[i][3]);
            }
        }
        __syncthreads();   // all stage-1 reads of AB done

        #pragma unroll
        for (int i = 0; i < 4; i++) {
            float g0 = fmaxf(fmaf(acc[i][0] + bb0, scv.x, shv.x), 0.0f);
            float g1 = fmaxf(fmaf(acc[i][1] + bb1, scv.y, shv.y), 0.0f);
            float g2 = fmaxf(fmaf(acc[i][2] + bb2, scv.z, shv.z), 0.0f);
            float g3 = fmaxf(fmaf(acc[i][3] + bb3, scv.w, shv.w), 0.0f);
            *(float4*)&AB[(ty * 4 + i) * 132 + tx * 4] = make_float4(g0, g1, g2, g3);
        }
        __syncthreads();   // B visible

        float acc2[4][2];
        #pragma unroll
        for (int i = 0; i < 4; i++) { acc2[i][0] = 0.0f; acc2[i][1] = 0.0f; }

        #pragma unroll 4
        for (int k4 = 0; k4 < 32; k4++) {
            float2 u0 = *(const float2*)&W2t[(k4 * 4 + 0) * 66 + tx * 2];
            float2 u1 = *(const float2*)&W2t[(k4 * 4 + 1) * 66 + tx * 2];
            float2 u2 = *(const float2*)&W2t[(k4 * 4 + 2) * 66 + tx * 2];
            float2 u3 = *(const float2*)&W2t[(k4 * 4 + 3) * 66 + tx * 2];
            #pragma unroll
            for (int i = 0; i < 4; i++) {
                float4 b = *(const float4*)&AB[(ty * 4 + i) * 132 + k4 * 4];
                acc2[i][0] = fmaf(b.x, u0.x, acc2[i][0]);
                acc2[i][1] = fmaf(b.x, u0.y, acc2[i][1]);
                acc2[i][0] = fmaf(b.y, u1.x, acc2[i][0]);
                acc2[i][1] = fmaf(b.y, u1.y, acc2[i][1]);
                acc2[i][0] = fmaf(b.z, u2.x, acc2[i][0]);
                acc2[i][1] = fmaf(b.z, u2.y, acc2[i][1]);
                acc2[i][0] = fmaf(b.w, u3.x, acc2[i][0]);
                acc2[i][1] = fmaf(b.w, u3.y, acc2[i][1]);
            }
        }

        #pragma unroll
        for (int i = 0; i < 4; i++) {
            int gr = row0 + ty * 4 + i;
            if (gr < N) {
                float2 pk = make_float2(acc2[i][0] + ob0, acc2[i][1] + ob1);
                ((float2*)out)[(size_t)gr * 32 + tx] = pk;
            }
        }
    }
}

// ---------------------------------------------------------------------------
extern "C" void kernel_launch(void* const* d_in, const int* in_sizes, int n_in,
                              void* d_out, int out_size, void* d_ws, size_t ws_size,
                              hipStream_t stream)
{
    const float* nf    = (const float*)d_in[0];
    const int*   ef    = (const int*)d_in[1];
    const int*   ei    = (const int*)d_in[2];
    const float* epsp  = (const float*)d_in[5];
    const float* be0   = (const float*)d_in[6];
    const float* be1   = (const float*)d_in[7];
    const float* be2   = (const float*)d_in[8];
    const float* W1    = (const float*)d_in[9];
    const float* b1    = (const float*)d_in[10];
    const float* gamma = (const float*)d_in[11];
    const float* beta  = (const float*)d_in[12];
    const float* W2    = (const float*)d_in[13];
    const float* b2v   = (const float*)d_in[14];
    float*       out   = (float*)d_out;

    int N = in_sizes[0] / D;    // 100000
    int E = in_sizes[1] / 3;    // 1600000
    int NB = (N + CHUNK - 1) / CHUNK;

    int tiles1 = (N + 63) / 64;              // 1563
    int g1     = (tiles1 + 2) / 3;           // 521 (each block: 3 tiles)
    int tiles2 = (N + 31) / 32;              // 3125
    int g2     = 256;                        // 1 block/CU (84.5 KB LDS)

    // workspace layout (4-byte elements)
    float* h       = (float*)d_ws;                    // N*64
    float* partials= h + (size_t)N * D;               // g1*256
    float* ss      = partials + (size_t)g1 * 256;     // 256
    float* embsum  = ss + 256;                        // 60*64
    int*   cnt     = (int*)(embsum + 60 * D);         // N
    int*   offs    = cnt + N;                         // N+1
    int*   bsum    = offs + N + 1;                    // NB
    int*   boff    = bsum + NB;                       // NB
    int*   payload = boff + NB;                       // E

    hipMemsetAsync(cnt, 0, (size_t)N * sizeof(int), stream);

    k_embsum<<<60, 64, 0, stream>>>(be0, be1, be2, embsum);

    int eBlocks = (E + 255) / 256;
    k_hist<<<eBlocks, 256, 0, stream>>>(ei, cnt, E);
    k_scan1<<<NB, 256, 0, stream>>>(cnt, offs, bsum, N);
    k_scan2<<<1, 128, 0, stream>>>(bsum, boff, NB);
    k_scan3<<<(N + 255) / 256, 256, 0, stream>>>(offs, cnt, boff, N, E);
    k_scatter<<<eBlocks, 256, 0, stream>>>(ei, ef, cnt, payload, E);

    k_reduce<<<(N + 3) / 4, 256, 0, stream>>>(nf, offs, payload, embsum, epsp, h, N);

    k_gemm1_stats<<<g1, 256, 0, stream>>>(h, W1, b1, partials, N, tiles1);
    k_stats_final<<<1, 128, 0, stream>>>(partials, g1, gamma, beta, ss, 1.0f / (float)N);
    k_gemm2<<<g2, 256, 0, stream>>>(h, W1, b1, ss, W2, b2v, out, N, tiles2);
}

// Round 6
// 651.585 us; speedup vs baseline: 2.8388x; 1.0396x over previous
//
#include <hip/hip_runtime.h>
#include <stdint.h>

#define D  64
#define D2 128
#define CHUNK 1024

// ---------------------------------------------------------------------------
// Embedding-sum table: embsum[code][0:64], code = f0*12 + f1*2 + f2 (60 codes)
// ---------------------------------------------------------------------------
__global__ void k_embsum(
    const float* __restrict__ be0, const float* __restrict__ be1,
    const float* __restrict__ be2, float* __restrict__ embsum)
{
    int c = blockIdx.x;      // 0..59
    int t = threadIdx.x;     // 0..63
    int f0 = c / 12;
    int r  = c % 12;
    int f1 = r / 2;
    int f2 = r % 2;
    embsum[c * D + t] = be0[f0 * D + t] + be1[f1 * D + t] + be2[f2 * D + t];
}

// ---------------------------------------------------------------------------
__global__ __launch_bounds__(256) void k_hist(
    const int* __restrict__ ei, int* __restrict__ cnt, int E)
{
    int e = blockIdx.x * 256 + threadIdx.x;
    if (e >= E) return;
    atomicAdd(&cnt[ei[e]], 1);
}

// ---------------------------------------------------------------------------
__global__ __launch_bounds__(256) void k_scan1(
    const int* __restrict__ cnt, int* __restrict__ offs,
    int* __restrict__ bsum, int N)
{
    __shared__ int sd[256];
    int t    = threadIdx.x;
    int i0   = blockIdx.x * CHUNK + t * 4;
    int v0 = (i0 + 0 < N) ? cnt[i0 + 0] : 0;
    int v1 = (i0 + 1 < N) ? cnt[i0 + 1] : 0;
    int v2 = (i0 + 2 < N) ? cnt[i0 + 2] : 0;
    int v3 = (i0 + 3 < N) ? cnt[i0 + 3] : 0;
    int s = v0 + v1 + v2 + v3;
    sd[t] = s;
    __syncthreads();
    for (int off = 1; off < 256; off <<= 1) {
        int x = (t >= off) ? sd[t - off] : 0;
        __syncthreads();
        sd[t] += x;
        __syncthreads();
    }
    int excl = sd[t] - s;
    if (t == 255) bsum[blockIdx.x] = sd[255];
    if (i0 + 0 < N) offs[i0 + 0] = excl;
    if (i0 + 1 < N) offs[i0 + 1] = excl + v0;
    if (i0 + 2 < N) offs[i0 + 2] = excl + v0 + v1;
    if (i0 + 3 < N) offs[i0 + 3] = excl + v0 + v1 + v2;
}

__global__ void k_scan2(const int* __restrict__ bsum, int* __restrict__ boff, int NB)
{
    __shared__ int sd[128];
    int t = threadIdx.x;
    int v = (t < NB) ? bsum[t] : 0;
    sd[t] = v;
    __syncthreads();
    for (int off = 1; off < 128; off <<= 1) {
        int x = (t >= off) ? sd[t - off] : 0;
        __syncthreads();
        sd[t] += x;
        __syncthreads();
    }
    if (t < NB) boff[t] = sd[t] - v;
}

__global__ __launch_bounds__(256) void k_scan3(
    int* __restrict__ offs, int* __restrict__ cnt,
    const int* __restrict__ boff, int N, int E)
{
    int i = blockIdx.x * 256 + threadIdx.x;
    if (i < N) {
        int o = offs[i] + boff[i / CHUNK];
        offs[i] = o;
        cnt[i]  = o;
    }
    if (i == 0) offs[N] = E;
}

// ---------------------------------------------------------------------------
__global__ __launch_bounds__(256) void k_scatter(
    const int* __restrict__ ei, const int* __restrict__ ef,
    int* __restrict__ cursor, int* __restrict__ payload, int E)
{
    int e = blockIdx.x * 256 + threadIdx.x;
    if (e >= E) return;
    int dst = ei[e];
    int src = ei[E + e];
    int code = ef[3 * e + 0] * 12 + ef[3 * e + 1] * 2 + ef[3 * e + 2];
    int pos = atomicAdd(&cursor[dst], 1);
    payload[pos] = src | (code << 17);
}

// ---------------------------------------------------------------------------
// Gather-reduce + fuse h = (1+eps)*nf + msg. One wave per node, lane=feature.
// 4-way unrolled edge loop for memory-level parallelism.
// ---------------------------------------------------------------------------
__global__ __launch_bounds__(256) void k_reduce(
    const float* __restrict__ nf,
    const int* __restrict__ offs,
    const int* __restrict__ payload,
    const float* __restrict__ embsum,
    const float* __restrict__ epsp,
    float* __restrict__ h, int N)
{
    __shared__ float sE[60 * D];   // 15 KB
    int tid = threadIdx.x;
    for (int i = tid; i < 60 * D; i += 256) sE[i] = embsum[i];
    __syncthreads();

    int n = (blockIdx.x * 256 + tid) >> 6;
    int l = tid & 63;
    if (n >= N) return;

    int start = offs[n];
    int end   = offs[n + 1];
    float acc = 0.0f;
    for (int jb = start; jb < end; jb += 64) {
        int u = (jb + l < end) ? payload[jb + l] : 0;
        int m = end - jb; if (m > 64) m = 64;
        int t = 0;
        for (; t + 4 <= m; t += 4) {
            int a0 = __shfl(u, t + 0);
            int a1 = __shfl(u, t + 1);
            int a2 = __shfl(u, t + 2);
            int a3 = __shfl(u, t + 3);
            float x0 = nf[(size_t)(a0 & 0x1FFFF) * D + l];
            float x1 = nf[(size_t)(a1 & 0x1FFFF) * D + l];
            float x2 = nf[(size_t)(a2 & 0x1FFFF) * D + l];
            float x3 = nf[(size_t)(a3 & 0x1FFFF) * D + l];
            float e0 = sE[(a0 >> 17) * D + l];
            float e1 = sE[(a1 >> 17) * D + l];
            float e2 = sE[(a2 >> 17) * D + l];
            float e3 = sE[(a3 >> 17) * D + l];
            acc += fmaxf(x0 + e0, 0.0f) + fmaxf(x1 + e1, 0.0f)
                 + fmaxf(x2 + e2, 0.0f) + fmaxf(x3 + e3, 0.0f);
        }
        for (; t < m; t++) {
            int a = __shfl(u, t);
            acc += fmaxf(nf[(size_t)(a & 0x1FFFF) * D + l] + sE[(a >> 17) * D + l], 0.0f);
        }
    }
    float epsv = 1.0f + epsp[0];
    h[(size_t)n * D + l] = fmaf(epsv, nf[(size_t)n * D + l], acc);
}

// ---------------------------------------------------------------------------
// BN stats via second moment: per-block partials of s = sum_n h_n (64) and
// M = sum_n h_n h_n^T (64x64). Lane l holds M[.][l] column in registers.
// var_c = w_c^T Mbar w_c - (w_c . sbar)^2  (b1 cancels exactly).
// ---------------------------------------------------------------------------
__global__ __launch_bounds__(256) void k_stats(
    const float* __restrict__ h,
    float* __restrict__ pM,     // [grid][4160]: M (4096) then s (64)
    int N, int nwaves)
{
    __shared__ float sM[65 * 66];   // 17160 B
    int tid = threadIdx.x;
    int wid = tid >> 6;
    int l   = tid & 63;

    float Mc[64];
    #pragma unroll
    for (int i = 0; i < 64; i++) Mc[i] = 0.0f;
    float sacc = 0.0f;

    for (int n = blockIdx.x * 4 + wid; n < N; n += nwaves) {
        float hl = h[(size_t)n * D + l];
        sacc += hl;
        #pragma unroll
        for (int i = 0; i < 64; i++) {
            float hi = __shfl(hl, i);
            Mc[i] = fmaf(hi, hl, Mc[i]);
        }
    }

    // serialize waves into sM
    for (int ww = 0; ww < 4; ww++) {
        __syncthreads();
        if (wid == ww) {
            if (ww == 0) {
                #pragma unroll
                for (int i = 0; i < 64; i++) sM[i * 66 + l] = Mc[i];
                sM[64 * 66 + l] = sacc;
            } else {
                #pragma unroll
                for (int i = 0; i < 64; i++) sM[i * 66 + l] += Mc[i];
                sM[64 * 66 + l] += sacc;
            }
        }
    }
    __syncthreads();

    float* P = pM + (size_t)blockIdx.x * 4160;
    for (int e = tid; e < 4160; e += 256) {
        int i = e >> 6, c = e & 63;
        P[e] = sM[i * 66 + c];
    }
}

// Reduce partials over blocks; pre-normalize by 1/N.
__global__ __launch_bounds__(256) void k_redM(
    const float* __restrict__ pM, int nblk,
    float* __restrict__ Mbar, float invN)
{
    int e = blockIdx.x * 256 + threadIdx.x;
    if (e >= 4160) return;
    float s = 0.0f;
    for (int b = 0; b < nblk; b++) s += pM[(size_t)b * 4160 + e];
    Mbar[e] = s * invN;
}

// Per-channel BN scale/shift from Mbar, sbar, W1, b1.
__global__ void k_bn(
    const float* __restrict__ Mbar,   // [4160]: M (64x64) then sbar (64)
    const float* __restrict__ W1,     // [128,64]
    const float* __restrict__ b1,
    const float* __restrict__ gamma, const float* __restrict__ beta,
    float* __restrict__ ss)
{
    __shared__ float sMb[4160];
    int tid = threadIdx.x;  // 128 threads
    for (int i = tid; i < 4160; i += 128) sMb[i] = Mbar[i];
    __syncthreads();

    int c = tid;
    float w[64];
    #pragma unroll
    for (int k = 0; k < 64; k++) w[k] = W1[c * D + k];

    float d = 0.0f;
    #pragma unroll
    for (int k = 0; k < 64; k++) d = fmaf(w[k], sMb[4096 + k], d);

    float Q = 0.0f;
    for (int k = 0; k < 64; k++) {
        float tk = 0.0f;
        #pragma unroll
        for (int j = 0; j < 64; j++) tk = fmaf(sMb[k * 64 + j], w[j], tk);
        Q = fmaf(w[k], tk, Q);
    }

    float var  = fmaxf(Q - d * d, 0.0f);
    float mean = d + b1[c];
    float sc   = gamma[c] * rsqrtf(var + 1e-5f);
    ss[c]       = sc;
    ss[128 + c] = beta[c] - mean * sc;
}

// ---------------------------------------------------------------------------
// GEMM2: persistent blocks, 32-row tiles, W1t/W2t staged once.
// LDS = 16384 + 32768 + 32768 = 81920 B exactly -> 2 blocks/CU.
// Pitches: AB 128, W1t 128, W2t 64 (reads are pitch-independent: full-row
// coverage or broadcast; only the tile stage-write pays a small conflict).
// Thread (ty,tx): rows ty*4..+3; stage1 cols tx*4..+3; stage2 cols tx*2..+1.
// ---------------------------------------------------------------------------
__global__ __launch_bounds__(256) void k_gemm2(
    const float* __restrict__ h,
    const float* __restrict__ W1,    // [128,64]
    const float* __restrict__ b1,    // [128]
    const float* __restrict__ ss,    // scale/shift [256]
    const float* __restrict__ W2,    // [64,128]
    const float* __restrict__ b2v,   // [64]
    float* __restrict__ out,         // [N,64]
    int N, int tiles)
{
    __shared__ float AB[32 * 128];    // 16384 B, both phases
    __shared__ float W1t[64 * 128];   // 32768 B
    __shared__ float W2t[128 * 64];   // 32768 B

    int tid = threadIdx.x;
    int ty = tid >> 5, tx = tid & 31;

    {   // stage W1^T: W1t[k][c]
        int c  = tid >> 1;
        int k0 = (tid & 1) * 32;
        const float4* wr = (const float4*)(W1 + c * D + k0);
        #pragma unroll
        for (int q = 0; q < 8; q++) {
            float4 u = wr[q];
            int k = k0 + q * 4;
            W1t[(k + 0) * 128 + c] = u.x;
            W1t[(k + 1) * 128 + c] = u.y;
            W1t[(k + 2) * 128 + c] = u.z;
            W1t[(k + 3) * 128 + c] = u.w;
        }
    }
    {   // stage W2^T: W2t[k][j]
        int j  = tid >> 2;
        int k0 = (tid & 3) * 32;
        const float4* wr = (const float4*)(W2 + j * D2 + k0);
        #pragma unroll
        for (int q = 0; q < 8; q++) {
            float4 u = wr[q];
            int k = k0 + q * 4;
            W2t[(k + 0) * 64 + j] = u.x;
            W2t[(k + 1) * 64 + j] = u.y;
            W2t[(k + 2) * 64 + j] = u.z;
            W2t[(k + 3) * 64 + j] = u.w;
        }
    }

    float bb0 = b1[tx * 4 + 0];
    float bb1 = b1[tx * 4 + 1];
    float bb2 = b1[tx * 4 + 2];
    float bb3 = b1[tx * 4 + 3];
    float4 scv = *(const float4*)&ss[tx * 4];
    float4 shv = *(const float4*)&ss[128 + tx * 4];
    float ob0 = b2v[tx * 2 + 0];
    float ob1 = b2v[tx * 2 + 1];

    for (int t = blockIdx.x; t < tiles; t += gridDim.x) {
        int row0 = t * 32;
        __syncthreads();   // protect AB from previous stage-2 reads (& W staging, iter 0)
        {   // phase A: stage h tile (cols 0..63)
            int r  = tid >> 3;
            int c8 = (tid & 7) * 8;
            int gr = row0 + r;
            float* dstp = &AB[r * 128 + c8];
            if (gr < N) {
                const float4* hrow = (const float4*)(h + (size_t)gr * D + c8);
                ((float4*)dstp)[0] = hrow[0];
                ((float4*)dstp)[1] = hrow[1];
            } else {
                #pragma unroll
                for (int m = 0; m < 8; m++) dstp[m] = 0.0f;
            }
        }
        __syncthreads();

        float acc[4][4];
        #pragma unroll
        for (int i = 0; i < 4; i++)
            #pragma unroll
            for (int j = 0; j < 4; j++) acc[i][j] = 0.0f;

        #pragma unroll 4
        for (int k4 = 0; k4 < 16; k4++) {
            float4 w0 = *(const float4*)&W1t[(k4 * 4 + 0) * 128 + tx * 4];
            float4 w1 = *(const float4*)&W1t[(k4 * 4 + 1) * 128 + tx * 4];
            float4 w2 = *(const float4*)&W1t[(k4 * 4 + 2) * 128 + tx * 4];
            float4 w3 = *(const float4*)&W1t[(k4 * 4 + 3) * 128 + tx * 4];
            #pragma unroll
            for (int i = 0; i < 4; i++) {
                float4 a = *(const float4*)&AB[(ty * 4 + i) * 128 + k4 * 4];
                acc[i][0] = fmaf(a.x, w0.x, acc[i][0]);
                acc[i][1] = fmaf(a.x, w0.y, acc[i][1]);
                acc[i][2] = fmaf(a.x, w0.z, acc[i][2]);
                acc[i][3] = fmaf(a.x, w0.w, acc[i][3]);
                acc[i][0] = fmaf(a.y, w1.x, acc[i][0]);
                acc[i][1] = fmaf(a.y, w1.y, acc[i][1]);
                acc[i][2] = fmaf(a.y, w1.z, acc[i][2]);
                acc[i][3] = fmaf(a.y, w1.w, acc[i][3]);
                acc[i][0] = fmaf(a.z, w2.x, acc[i][0]);
                acc[i][1] = fmaf(a.z, w2.y, acc[i][1]);
                acc[i][2] = fmaf(a.z, w2.z, acc[i][2]);
                acc[i][3] = fmaf(a.z, w2.w, acc[i][3]);
                acc[i][0] = fmaf(a.w, w3.x, acc[i][0]);
                acc[i][1] = fmaf(a.w, w3.y, acc[i][1]);
                acc[i][2] = fmaf(a.w, w3.z, acc[i][2]);
                acc[i][3] = fmaf(a.w, w3.w, acc[i][3]);
            }
        }
        __syncthreads();   // all stage-1 reads of AB done

        #pragma unroll
        for (int i = 0; i < 4; i++) {
            float g0 = fmaxf(fmaf(acc[i][0] + bb0, scv.x, shv.x), 0.0f);
            float g1 = fmaxf(fmaf(acc[i][1] + bb1, scv.y, shv.y), 0.0f);
            float g2 = fmaxf(fmaf(acc[i][2] + bb2, scv.z, shv.z), 0.0f);
            float g3 = fmaxf(fmaf(acc[i][3] + bb3, scv.w, shv.w), 0.0f);
            *(float4*)&AB[(ty * 4 + i) * 128 + tx * 4] = make_float4(g0, g1, g2, g3);
        }
        __syncthreads();   // B visible

        float acc2[4][2];
        #pragma unroll
        for (int i = 0; i < 4; i++) { acc2[i][0] = 0.0f; acc2[i][1] = 0.0f; }

        #pragma unroll 4
        for (int k4 = 0; k4 < 32; k4++) {
            float2 u0 = *(const float2*)&W2t[(k4 * 4 + 0) * 64 + tx * 2];
            float2 u1 = *(const float2*)&W2t[(k4 * 4 + 1) * 64 + tx * 2];
            float2 u2 = *(const float2*)&W2t[(k4 * 4 + 2) * 64 + tx * 2];
            float2 u3 = *(const float2*)&W2t[(k4 * 4 + 3) * 64 + tx * 2];
            #pragma unroll
            for (int i = 0; i < 4; i++) {
                float4 b = *(const float4*)&AB[(ty * 4 + i) * 128 + k4 * 4];
                acc2[i][0] = fmaf(b.x, u0.x, acc2[i][0]);
                acc2[i][1] = fmaf(b.x, u0.y, acc2[i][1]);
                acc2[i][0] = fmaf(b.y, u1.x, acc2[i][0]);
                acc2[i][1] = fmaf(b.y, u1.y, acc2[i][1]);
                acc2[i][0] = fmaf(b.z, u2.x, acc2[i][0]);
                acc2[i][1] = fmaf(b.z, u2.y, acc2[i][1]);
                acc2[i][0] = fmaf(b.w, u3.x, acc2[i][0]);
                acc2[i][1] = fmaf(b.w, u3.y, acc2[i][1]);
            }
        }

        #pragma unroll
        for (int i = 0; i < 4; i++) {
            int gr = row0 + ty * 4 + i;
            if (gr < N) {
                float2 pk = make_float2(acc2[i][0] + ob0, acc2[i][1] + ob1);
                ((float2*)out)[(size_t)gr * 32 + tx] = pk;
            }
        }
    }
}

// ---------------------------------------------------------------------------
extern "C" void kernel_launch(void* const* d_in, const int* in_sizes, int n_in,
                              void* d_out, int out_size, void* d_ws, size_t ws_size,
                              hipStream_t stream)
{
    const float* nf    = (const float*)d_in[0];
    const int*   ef    = (const int*)d_in[1];
    const int*   ei    = (const int*)d_in[2];
    const float* epsp  = (const float*)d_in[5];
    const float* be0   = (const float*)d_in[6];
    const float* be1   = (const float*)d_in[7];
    const float* be2   = (const float*)d_in[8];
    const float* W1    = (const float*)d_in[9];
    const float* b1    = (const float*)d_in[10];
    const float* gamma = (const float*)d_in[11];
    const float* beta  = (const float*)d_in[12];
    const float* W2    = (const float*)d_in[13];
    const float* b2v   = (const float*)d_in[14];
    float*       out   = (float*)d_out;

    int N = in_sizes[0] / D;    // 100000
    int E = in_sizes[1] / 3;    // 1600000
    int NB = (N + CHUNK - 1) / CHUNK;

    int gS = 256;                     // k_stats blocks (4 waves each)
    int tiles2 = (N + 31) / 32;       // 3125
    int g2 = 512;                     // 2 blocks/CU

    // workspace layout (4-byte elements)
    float* h       = (float*)d_ws;                    // N*64
    float* pM      = h + (size_t)N * D;               // gS*4160
    float* Mbar    = pM + (size_t)gS * 4160;          // 4160
    float* ss      = Mbar + 4160;                     // 256
    float* embsum  = ss + 256;                        // 60*64
    int*   cnt     = (int*)(embsum + 60 * D);         // N
    int*   offs    = cnt + N;                         // N+1
    int*   bsum    = offs + N + 1;                    // NB
    int*   boff    = bsum + NB;                       // NB
    int*   payload = boff + NB;                       // E

    hipMemsetAsync(cnt, 0, (size_t)N * sizeof(int), stream);

    k_embsum<<<60, 64, 0, stream>>>(be0, be1, be2, embsum);

    int eBlocks = (E + 255) / 256;
    k_hist<<<eBlocks, 256, 0, stream>>>(ei, cnt, E);
    k_scan1<<<NB, 256, 0, stream>>>(cnt, offs, bsum, N);
    k_scan2<<<1, 128, 0, stream>>>(bsum, boff, NB);
    k_scan3<<<(N + 255) / 256, 256, 0, stream>>>(offs, cnt, boff, N, E);
    k_scatter<<<eBlocks, 256, 0, stream>>>(ei, ef, cnt, payload, E);

    k_reduce<<<(N + 3) / 4, 256, 0, stream>>>(nf, offs, payload, embsum, epsp, h, N);

    k_stats<<<gS, 256, 0, stream>>>(h, pM, N, gS * 4);
    k_redM<<<(4160 + 255) / 256, 256, 0, stream>>>(pM, gS, Mbar, 1.0f / (float)N);
    k_bn<<<1, 128, 0, stream>>>(Mbar, W1, b1, gamma, beta, ss);

    k_gemm2<<<g2, 256, 0, stream>>>(h, W1, b1, ss, W2, b2v, out, N, tiles2);
}

// Round 7
// 612.013 us; speedup vs baseline: 3.0224x; 1.0647x over previous
//
#include <hip/hip_runtime.h>
#include <stdint.h>

#define D  64
#define D2 128
#define CHUNK 1024

// ---------------------------------------------------------------------------
__global__ __launch_bounds__(256) void k_hist(
    const int* __restrict__ ei, int* __restrict__ cnt, int E)
{
    int e = blockIdx.x * 256 + threadIdx.x;
    if (e >= E) return;
    atomicAdd(&cnt[ei[e]], 1);
}

// ---------------------------------------------------------------------------
__global__ __launch_bounds__(256) void k_scan1(
    const int* __restrict__ cnt, int* __restrict__ offs,
    int* __restrict__ bsum, int N)
{
    __shared__ int sd[256];
    int t    = threadIdx.x;
    int i0   = blockIdx.x * CHUNK + t * 4;
    int v0 = (i0 + 0 < N) ? cnt[i0 + 0] : 0;
    int v1 = (i0 + 1 < N) ? cnt[i0 + 1] : 0;
    int v2 = (i0 + 2 < N) ? cnt[i0 + 2] : 0;
    int v3 = (i0 + 3 < N) ? cnt[i0 + 3] : 0;
    int s = v0 + v1 + v2 + v3;
    sd[t] = s;
    __syncthreads();
    for (int off = 1; off < 256; off <<= 1) {
        int x = (t >= off) ? sd[t - off] : 0;
        __syncthreads();
        sd[t] += x;
        __syncthreads();
    }
    int excl = sd[t] - s;
    if (t == 255) bsum[blockIdx.x] = sd[255];
    if (i0 + 0 < N) offs[i0 + 0] = excl;
    if (i0 + 1 < N) offs[i0 + 1] = excl + v0;
    if (i0 + 2 < N) offs[i0 + 2] = excl + v0 + v1;
    if (i0 + 3 < N) offs[i0 + 3] = excl + v0 + v1 + v2;
}

__global__ void k_scan2(const int* __restrict__ bsum, int* __restrict__ boff, int NB)
{
    __shared__ int sd[128];
    int t = threadIdx.x;
    int v = (t < NB) ? bsum[t] : 0;
    sd[t] = v;
    __syncthreads();
    for (int off = 1; off < 128; off <<= 1) {
        int x = (t >= off) ? sd[t - off] : 0;
        __syncthreads();
        sd[t] += x;
        __syncthreads();
    }
    if (t < NB) boff[t] = sd[t] - v;
}

__global__ __launch_bounds__(256) void k_scan3(
    int* __restrict__ offs, int* __restrict__ cnt,
    const int* __restrict__ boff, int N, int E)
{
    int i = blockIdx.x * 256 + threadIdx.x;
    if (i < N) {
        int o = offs[i] + boff[i / CHUNK];
        offs[i] = o;
        cnt[i]  = o;
    }
    if (i == 0) offs[N] = E;
}

// ---------------------------------------------------------------------------
// Scatter: payload[pos] = src*256 + code (byte-offset-friendly packing).
// ---------------------------------------------------------------------------
__global__ __launch_bounds__(256) void k_scatter(
    const int* __restrict__ ei, const int* __restrict__ ef,
    int* __restrict__ cursor, int* __restrict__ payload, int E)
{
    int e = blockIdx.x * 256 + threadIdx.x;
    if (e >= E) return;
    int dst = ei[e];
    int src = ei[E + e];
    int code = ef[3 * e + 0] * 12 + ef[3 * e + 1] * 2 + ef[3 * e + 2];
    int pos = atomicAdd(&cursor[dst], 1);
    payload[pos] = (src << 8) | code;
}

// ---------------------------------------------------------------------------
// Gather-reduce + fuse h = (1+eps)*nf + msg. One wave per node, lane=feature.
// Edge words are wave-uniform: scalarize via readfirstlane so per-edge address
// math runs on the SALU pipe; nf loads use saddr + constant voffset l*4.
// Also builds the 60x64 embedding-sum table in LDS (k_embsum folded in).
// ---------------------------------------------------------------------------
__global__ __launch_bounds__(256) void k_reduce(
    const float* __restrict__ nf,
    const int* __restrict__ offs,
    const int* __restrict__ payload,
    const float* __restrict__ be0, const float* __restrict__ be1,
    const float* __restrict__ be2,
    const float* __restrict__ epsp,
    float* __restrict__ h, int N)
{
    __shared__ float sE[60 * D];   // 15 KB
    int tid = threadIdx.x;
    for (int i = tid; i < 60 * D; i += 256) {
        int c = i >> 6, l = i & 63;
        int f0 = c / 12, r = c % 12;
        sE[i] = be0[f0 * D + l] + be1[(r >> 1) * D + l] + be2[(r & 1) * D + l];
    }
    __syncthreads();

    int n = __builtin_amdgcn_readfirstlane((blockIdx.x * 256 + tid) >> 6);
    int l = tid & 63;
    if (n >= N) return;

    int s0 = offs[n];
    int s1 = offs[n + 1];
    float acc = 0.0f;
    int t = s0;
    for (; t + 4 <= s1; t += 4) {
        int u0 = __builtin_amdgcn_readfirstlane(payload[t + 0]);
        int u1 = __builtin_amdgcn_readfirstlane(payload[t + 1]);
        int u2 = __builtin_amdgcn_readfirstlane(payload[t + 2]);
        int u3 = __builtin_amdgcn_readfirstlane(payload[t + 3]);
        float x0 = nf[((u0 >> 8) << 6) + l];
        float x1 = nf[((u1 >> 8) << 6) + l];
        float x2 = nf[((u2 >> 8) << 6) + l];
        float x3 = nf[((u3 >> 8) << 6) + l];
        float e0 = sE[((u0 & 255) << 6) + l];
        float e1 = sE[((u1 & 255) << 6) + l];
        float e2 = sE[((u2 & 255) << 6) + l];
        float e3 = sE[((u3 & 255) << 6) + l];
        acc += fmaxf(x0 + e0, 0.0f) + fmaxf(x1 + e1, 0.0f)
             + fmaxf(x2 + e2, 0.0f) + fmaxf(x3 + e3, 0.0f);
    }
    for (; t < s1; t++) {
        int u = __builtin_amdgcn_readfirstlane(payload[t]);
        acc += fmaxf(nf[((u >> 8) << 6) + l] + sE[((u & 255) << 6) + l], 0.0f);
    }
    float epsv = 1.0f + epsp[0];
    h[(size_t)n * D + l] = fmaf(epsv, nf[(size_t)n * D + l], acc);
}

// ---------------------------------------------------------------------------
// BN stats, syrk-style: per-block register-accumulated partials of
// M = sum_n h_n h_n^T (64x64, 16x16 threads x 4x4 regs) and s = sum_n h_n.
// ---------------------------------------------------------------------------
__global__ __launch_bounds__(256) void k_stats(
    const float* __restrict__ h,
    float* __restrict__ pM,     // [grid][4160]: M (4096) then s (64)
    int N, int tiles)
{
    __shared__ float sH[64 * 68];   // 17408 B
    __shared__ float sred[4 * 64];
    int tid = threadIdx.x;
    int iB = tid >> 4, jB = tid & 15;
    int rg = tid >> 6, lc = tid & 63;

    float M[4][4];
    #pragma unroll
    for (int a = 0; a < 4; a++)
        #pragma unroll
        for (int b = 0; b < 4; b++) M[a][b] = 0.0f;
    float sp = 0.0f;

    for (int t = blockIdx.x; t < tiles; t += gridDim.x) {
        int row0 = t * 64;
        __syncthreads();   // protect sH from previous iteration's reads
        {
            int r = tid >> 2, c16 = (tid & 3) * 16;
            int gr = row0 + r;
            float* dp = &sH[r * 68 + c16];
            if (gr < N) {
                const float4* hr = (const float4*)(h + (size_t)gr * D + c16);
                #pragma unroll
                for (int m2 = 0; m2 < 4; m2++) ((float4*)dp)[m2] = hr[m2];
            } else {
                #pragma unroll
                for (int m2 = 0; m2 < 16; m2++) dp[m2] = 0.0f;
            }
        }
        __syncthreads();

        #pragma unroll 8
        for (int n2 = 0; n2 < 64; n2++) {
            float4 a = *(const float4*)&sH[n2 * 68 + iB * 4];
            float4 b = *(const float4*)&sH[n2 * 68 + jB * 4];
            M[0][0] = fmaf(a.x, b.x, M[0][0]);
            M[0][1] = fmaf(a.x, b.y, M[0][1]);
            M[0][2] = fmaf(a.x, b.z, M[0][2]);
            M[0][3] = fmaf(a.x, b.w, M[0][3]);
            M[1][0] = fmaf(a.y, b.x, M[1][0]);
            M[1][1] = fmaf(a.y, b.y, M[1][1]);
            M[1][2] = fmaf(a.y, b.z, M[1][2]);
            M[1][3] = fmaf(a.y, b.w, M[1][3]);
            M[2][0] = fmaf(a.z, b.x, M[2][0]);
            M[2][1] = fmaf(a.z, b.y, M[2][1]);
            M[2][2] = fmaf(a.z, b.z, M[2][2]);
            M[2][3] = fmaf(a.z, b.w, M[2][3]);
            M[3][0] = fmaf(a.w, b.x, M[3][0]);
            M[3][1] = fmaf(a.w, b.y, M[3][1]);
            M[3][2] = fmaf(a.w, b.z, M[3][2]);
            M[3][3] = fmaf(a.w, b.w, M[3][3]);
        }
        #pragma unroll
        for (int r2 = 0; r2 < 16; r2++)
            sp += sH[(rg * 16 + r2) * 68 + lc];
    }

    float* P = pM + (size_t)blockIdx.x * 4160;
    #pragma unroll
    for (int a = 0; a < 4; a++)
        #pragma unroll
        for (int b = 0; b < 4; b++)
            P[(iB * 4 + a) * 64 + jB * 4 + b] = M[a][b];
    sred[rg * 64 + lc] = sp;
    __syncthreads();
    if (tid < 64)
        P[4096 + tid] = sred[tid] + sred[64 + tid] + sred[128 + tid] + sred[192 + tid];
}

// Reduce partials over blocks; pre-normalize by 1/N.
__global__ __launch_bounds__(256) void k_redM(
    const float* __restrict__ pM, int nblk,
    float* __restrict__ Mbar, float invN)
{
    int e = blockIdx.x * 256 + threadIdx.x;
    if (e >= 4160) return;
    float s = 0.0f;
    for (int b = 0; b < nblk; b++) s += pM[(size_t)b * 4160 + e];
    Mbar[e] = s * invN;
}

// Per-channel BN scale/shift: var_c = w^T Mbar w - (w.sbar)^2, mean = w.sbar+b1.
__global__ void k_bn(
    const float* __restrict__ Mbar,   // [4160]: M (64x64) then sbar (64)
    const float* __restrict__ W1,     // [128,64]
    const float* __restrict__ b1,
    const float* __restrict__ gamma, const float* __restrict__ beta,
    float* __restrict__ ss)
{
    __shared__ float sMb[4160];
    int tid = threadIdx.x;  // 128 threads
    for (int i = tid; i < 4160; i += 128) sMb[i] = Mbar[i];
    __syncthreads();

    int c = tid;
    float w[64];
    #pragma unroll
    for (int k = 0; k < 64; k++) w[k] = W1[c * D + k];

    float d = 0.0f;
    #pragma unroll
    for (int k = 0; k < 64; k++) d = fmaf(w[k], sMb[4096 + k], d);

    float Q = 0.0f;
    for (int k = 0; k < 64; k++) {
        float tk = 0.0f;
        #pragma unroll
        for (int j = 0; j < 64; j++) tk = fmaf(sMb[k * 64 + j], w[j], tk);
        Q = fmaf(w[k], tk, Q);
    }

    float var  = fmaxf(Q - d * d, 0.0f);
    float mean = d + b1[c];
    float sc   = gamma[c] * rsqrtf(var + 1e-5f);
    ss[c]       = sc;
    ss[128 + c] = beta[c] - mean * sc;
}

// ---------------------------------------------------------------------------
// GEMM2: persistent blocks, 32-row tiles, W1t/W2t staged once.
// LDS = 16384 + 32768 + 32768 = 81920 B exactly -> 2 blocks/CU.
// ---------------------------------------------------------------------------
__global__ __launch_bounds__(256) void k_gemm2(
    const float* __restrict__ h,
    const float* __restrict__ W1,    // [128,64]
    const float* __restrict__ b1,    // [128]
    const float* __restrict__ ss,    // scale/shift [256]
    const float* __restrict__ W2,    // [64,128]
    const float* __restrict__ b2v,   // [64]
    float* __restrict__ out,         // [N,64]
    int N, int tiles)
{
    __shared__ float AB[32 * 128];
    __shared__ float W1t[64 * 128];
    __shared__ float W2t[128 * 64];

    int tid = threadIdx.x;
    int ty = tid >> 5, tx = tid & 31;

    {   // stage W1^T: W1t[k][c]
        int c  = tid >> 1;
        int k0 = (tid & 1) * 32;
        const float4* wr = (const float4*)(W1 + c * D + k0);
        #pragma unroll
        for (int q = 0; q < 8; q++) {
            float4 u = wr[q];
            int k = k0 + q * 4;
            W1t[(k + 0) * 128 + c] = u.x;
            W1t[(k + 1) * 128 + c] = u.y;
            W1t[(k + 2) * 128 + c] = u.z;
            W1t[(k + 3) * 128 + c] = u.w;
        }
    }
    {   // stage W2^T: W2t[k][j]
        int j  = tid >> 2;
        int k0 = (tid & 3) * 32;
        const float4* wr = (const float4*)(W2 + j * D2 + k0);
        #pragma unroll
        for (int q = 0; q < 8; q++) {
            float4 u = wr[q];
            int k = k0 + q * 4;
            W2t[(k + 0) * 64 + j] = u.x;
            W2t[(k + 1) * 64 + j] = u.y;
            W2t[(k + 2) * 64 + j] = u.z;
            W2t[(k + 3) * 64 + j] = u.w;
        }
    }

    float bb0 = b1[tx * 4 + 0];
    float bb1 = b1[tx * 4 + 1];
    float bb2 = b1[tx * 4 + 2];
    float bb3 = b1[tx * 4 + 3];
    float4 scv = *(const float4*)&ss[tx * 4];
    float4 shv = *(const float4*)&ss[128 + tx * 4];
    float ob0 = b2v[tx * 2 + 0];
    float ob1 = b2v[tx * 2 + 1];

    for (int t = blockIdx.x; t < tiles; t += gridDim.x) {
        int row0 = t * 32;
        __syncthreads();
        {   // phase A: stage h tile (cols 0..63)
            int r  = tid >> 3;
            int c8 = (tid & 7) * 8;
            int gr = row0 + r;
            float* dstp = &AB[r * 128 + c8];
            if (gr < N) {
                const float4* hrow = (const float4*)(h + (size_t)gr * D + c8);
                ((float4*)dstp)[0] = hrow[0];
                ((float4*)dstp)[1] = hrow[1];
            } else {
                #pragma unroll
                for (int m = 0; m < 8; m++) dstp[m] = 0.0f;
            }
        }
        __syncthreads();

        float acc[4][4];
        #pragma unroll
        for (int i = 0; i < 4; i++)
            #pragma unroll
            for (int j = 0; j < 4; j++) acc[i][j] = 0.0f;

        #pragma unroll 4
        for (int k4 = 0; k4 < 16; k4++) {
            float4 w0 = *(const float4*)&W1t[(k4 * 4 + 0) * 128 + tx * 4];
            float4 w1 = *(const float4*)&W1t[(k4 * 4 + 1) * 128 + tx * 4];
            float4 w2 = *(const float4*)&W1t[(k4 * 4 + 2) * 128 + tx * 4];
            float4 w3 = *(const float4*)&W1t[(k4 * 4 + 3) * 128 + tx * 4];
            #pragma unroll
            for (int i = 0; i < 4; i++) {
                float4 a = *(const float4*)&AB[(ty * 4 + i) * 128 + k4 * 4];
                acc[i][0] = fmaf(a.x, w0.x, acc[i][0]);
                acc[i][1] = fmaf(a.x, w0.y, acc[i][1]);
                acc[i][2] = fmaf(a.x, w0.z, acc[i][2]);
                acc[i][3] = fmaf(a.x, w0.w, acc[i][3]);
                acc[i][0] = fmaf(a.y, w1.x, acc[i][0]);
                acc[i][1] = fmaf(a.y, w1.y, acc[i][1]);
                acc[i][2] = fmaf(a.y, w1.z, acc[i][2]);
                acc[i][3] = fmaf(a.y, w1.w, acc[i][3]);
                acc[i][0] = fmaf(a.z, w2.x, acc[i][0]);
                acc[i][1] = fmaf(a.z, w2.y, acc[i][1]);
                acc[i][2] = fmaf(a.z, w2.z, acc[i][2]);
                acc[i][3] = fmaf(a.z, w2.w, acc[i][3]);
                acc[i][0] = fmaf(a.w, w3.x, acc[i][0]);
                acc[i][1] = fmaf(a.w, w3.y, acc[i][1]);
                acc[i][2] = fmaf(a.w, w3.z, acc[i][2]);
                acc[i][3] = fmaf(a.w, w3.w, acc[i][3]);
            }
        }
        __syncthreads();

        #pragma unroll
        for (int i = 0; i < 4; i++) {
            float g0 = fmaxf(fmaf(acc[i][0] + bb0, scv.x, shv.x), 0.0f);
            float g1 = fmaxf(fmaf(acc[i][1] + bb1, scv.y, shv.y), 0.0f);
            float g2 = fmaxf(fmaf(acc[i][2] + bb2, scv.z, shv.z), 0.0f);
            float g3 = fmaxf(fmaf(acc[i][3] + bb3, scv.w, shv.w), 0.0f);
            *(float4*)&AB[(ty * 4 + i) * 128 + tx * 4] = make_float4(g0, g1, g2, g3);
        }
        __syncthreads();

        float acc2[4][2];
        #pragma unroll
        for (int i = 0; i < 4; i++) { acc2[i][0] = 0.0f; acc2[i][1] = 0.0f; }

        #pragma unroll 4
        for (int k4 = 0; k4 < 32; k4++) {
            float2 u0 = *(const float2*)&W2t[(k4 * 4 + 0) * 64 + tx * 2];
            float2 u1 = *(const float2*)&W2t[(k4 * 4 + 1) * 64 + tx * 2];
            float2 u2 = *(const float2*)&W2t[(k4 * 4 + 2) * 64 + tx * 2];
            float2 u3 = *(const float2*)&W2t[(k4 * 4 + 3) * 64 + tx * 2];
            #pragma unroll
            for (int i = 0; i < 4; i++) {
                float4 b = *(const float4*)&AB[(ty * 4 + i) * 128 + k4 * 4];
                acc2[i][0] = fmaf(b.x, u0.x, acc2[i][0]);
                acc2[i][1] = fmaf(b.x, u0.y, acc2[i][1]);
                acc2[i][0] = fmaf(b.y, u1.x, acc2[i][0]);
                acc2[i][1] = fmaf(b.y, u1.y, acc2[i][1]);
                acc2[i][0] = fmaf(b.z, u2.x, acc2[i][0]);
                acc2[i][1] = fmaf(b.z, u2.y, acc2[i][1]);
                acc2[i][0] = fmaf(b.w, u3.x, acc2[i][0]);
                acc2[i][1] = fmaf(b.w, u3.y, acc2[i][1]);
            }
        }

        #pragma unroll
        for (int i = 0; i < 4; i++) {
            int gr = row0 + ty * 4 + i;
            if (gr < N) {
                float2 pk = make_float2(acc2[i][0] + ob0, acc2[i][1] + ob1);
                ((float2*)out)[(size_t)gr * 32 + tx] = pk;
            }
        }
    }
}

// ---------------------------------------------------------------------------
extern "C" void kernel_launch(void* const* d_in, const int* in_sizes, int n_in,
                              void* d_out, int out_size, void* d_ws, size_t ws_size,
                              hipStream_t stream)
{
    const float* nf    = (const float*)d_in[0];
    const int*   ef    = (const int*)d_in[1];
    const int*   ei    = (const int*)d_in[2];
    const float* epsp  = (const float*)d_in[5];
    const float* be0   = (const float*)d_in[6];
    const float* be1   = (const float*)d_in[7];
    const float* be2   = (const float*)d_in[8];
    const float* W1    = (const float*)d_in[9];
    const float* b1    = (const float*)d_in[10];
    const float* gamma = (const float*)d_in[11];
    const float* beta  = (const float*)d_in[12];
    const float* W2    = (const float*)d_in[13];
    const float* b2v   = (const float*)d_in[14];
    float*       out   = (float*)d_out;

    int N = in_sizes[0] / D;    // 100000
    int E = in_sizes[1] / 3;    // 1600000
    int NB = (N + CHUNK - 1) / CHUNK;

    int gS = 256;                         // k_stats blocks
    int tilesS = (N + 63) / 64;           // 1563
    int tiles2 = (N + 31) / 32;           // 3125
    int g2 = 512;                         // 2 blocks/CU

    // workspace layout (4-byte elements)
    float* h       = (float*)d_ws;                    // N*64
    float* pM      = h + (size_t)N * D;               // gS*4160
    float* Mbar    = pM + (size_t)gS * 4160;          // 4160
    float* ss      = Mbar + 4160;                     // 256
    int*   cnt     = (int*)(ss + 256);                // N
    int*   offs    = cnt + N;                         // N+1
    int*   bsum    = offs + N + 1;                    // NB
    int*   boff    = bsum + NB;                       // NB
    int*   payload = boff + NB;                       // E

    hipMemsetAsync(cnt, 0, (size_t)N * sizeof(int), stream);

    int eBlocks = (E + 255) / 256;
    k_hist<<<eBlocks, 256, 0, stream>>>(ei, cnt, E);
    k_scan1<<<NB, 256, 0, stream>>>(cnt, offs, bsum, N);
    k_scan2<<<1, 128, 0, stream>>>(bsum, boff, NB);
    k_scan3<<<(N + 255) / 256, 256, 0, stream>>>(offs, cnt, boff, N, E);
    k_scatter<<<eBlocks, 256, 0, stream>>>(ei, ef, cnt, payload, E);

    k_reduce<<<(N + 3) / 4, 256, 0, stream>>>(nf, offs, payload, be0, be1, be2,
                                              epsp, h, N);

    k_stats<<<gS, 256, 0, stream>>>(h, pM, N, tilesS);
    k_redM<<<(4160 + 255) / 256, 256, 0, stream>>>(pM, gS, Mbar, 1.0f / (float)N);
    k_bn<<<1, 128, 0, stream>>>(Mbar, W1, b1, gamma, beta, ss);

    k_gemm2<<<g2, 256, 0, stream>>>(h, W1, b1, ss, W2, b2v, out, N, tiles2);
}